// Round 11
// baseline (377.157 us; speedup 1.0000x reference)
//
#include <hip/hip_runtime.h>
#include <hip/hip_bf16.h>
#include <math.h>

#define B_   4
#define S_   4096
#define D_   1024
#define H_   16
#define DH_  64
#define BS_  (B_ * S_)     // 16384 rows
#define N3_  3072          // 3 * INNER

using bf16 = __hip_bfloat16;
typedef __attribute__((ext_vector_type(8))) short bf16x8;
typedef __attribute__((ext_vector_type(4))) float f32x4;

#define GAS __attribute__((address_space(1)))
#define LAS __attribute__((address_space(3)))

__device__ __forceinline__ void gload_lds16(const bf16* g, bf16* l) {
  __builtin_amdgcn_global_load_lds((const GAS void*)g, (LAS void*)l, 16, 0, 0);
}

__device__ __forceinline__ float bf2f(short u) {
  unsigned int x = ((unsigned int)(unsigned short)u) << 16;
  return __builtin_bit_cast(float, x);
}
__device__ __forceinline__ unsigned short f2bfu(float f) {
  bf16 t = __float2bfloat16(f);
  return *(unsigned short*)&t;
}

// ------------- fused prep: LN1(+PE) AND 4x weight transpose, one launch ----
__global__ __launch_bounds__(256)
void prep_kernel(const float* __restrict__ x, const float* __restrict__ ln1_g,
                 const float* __restrict__ ln1_b, bf16* __restrict__ h,
                 const float* __restrict__ Wqkv, const float* __restrict__ Wo,
                 const float* __restrict__ W1, const float* __restrict__ W2,
                 bf16* __restrict__ wqkvt, bf16* __restrict__ wot,
                 bf16* __restrict__ w1t, bf16* __restrict__ w2t)
{
  int bid = blockIdx.x;
  int t = threadIdx.x;
  if (bid < BS_) {
    int row = bid;
    float4 v = ((const float4*)(x + (size_t)row * D_))[t];
    float s  = v.x + v.y + v.z + v.w;
    float ss = v.x * v.x + v.y * v.y + v.z * v.z + v.w * v.w;
#pragma unroll
    for (int o = 32; o > 0; o >>= 1) { s += __shfl_xor(s, o); ss += __shfl_xor(ss, o); }
    __shared__ float red[8];
    int wid = t >> 6, lane = t & 63;
    if (lane == 0) { red[wid] = s; red[4 + wid] = ss; }
    __syncthreads();
    s  = red[0] + red[1] + red[2] + red[3];
    ss = red[4] + red[5] + red[6] + red[7];
    float mean = s * (1.0f / D_);
    float var  = ss * (1.0f / D_) - mean * mean;
    float rs   = rsqrtf(var + 1e-6f);
    int d0 = t * 4;
    const float4 g4 = ((const float4*)ln1_g)[t];
    const float4 b4 = ((const float4*)ln1_b)[t];
    float o0 = (v.x - mean) * rs * g4.x + b4.x;
    float o1 = (v.y - mean) * rs * g4.y + b4.y;
    float o2 = (v.z - mean) * rs * g4.z + b4.z;
    float o3 = (v.w - mean) * rs * g4.w + b4.w;
    const float C = -0.0089944730194f;   // -ln(10000)/1024
    float p = (float)(row & (S_ - 1));
    float sn, cs;
    __sincosf(p * __expf((float)d0 * C), &sn, &cs);        o0 += sn; o1 += cs;
    __sincosf(p * __expf((float)(d0 + 2) * C), &sn, &cs);  o2 += sn; o3 += cs;
    ushort4 pk;
    pk.x = f2bfu(o0); pk.y = f2bfu(o1); pk.z = f2bfu(o2); pk.w = f2bfu(o3);
    ((ushort4*)h)[(size_t)row * (D_ / 4) + t] = pk;
  } else {
    int e = bid - BS_;
    int gx = e % 192, ky = e / 192;
    __shared__ float tile[32][33];
    const float* W; bf16* Wt; int N, xo;
    if (gx < 96)        { W = Wqkv; Wt = wqkvt; N = N3_; xo = gx; }
    else if (gx < 128)  { W = Wo;   Wt = wot;   N = D_;  xo = gx - 96; }
    else if (gx < 160)  { W = W1;   Wt = w1t;   N = D_;  xo = gx - 128; }
    else                { W = W2;   Wt = w2t;   N = D_;  xo = gx - 160; }
    int n0 = xo * 32, k0 = ky * 32;
    int tx = t & 31, ty = t >> 5;
#pragma unroll
    for (int j = 0; j < 32; j += 8)
      tile[ty + j][tx] = W[(size_t)(k0 + ty + j) * N + n0 + tx];
    __syncthreads();
#pragma unroll
    for (int j = 0; j < 32; j += 8)
      Wt[(size_t)(n0 + ty + j) * 1024 + k0 + tx] = __float2bfloat16(tile[tx][ty + j]);
  }
}

// ---------------- LayerNorm bf16-in -> bf16 (LN2) --------------------------
__global__ __launch_bounds__(256)
void ln_kernel(const bf16* __restrict__ Xb, const float* __restrict__ G,
               const float* __restrict__ Bv, bf16* __restrict__ out)
{
  int row = blockIdx.x;
  int t = threadIdx.x;
  ushort4 u = ((const ushort4*)Xb)[(size_t)row * (D_ / 4) + t];
  float4 v;
  v.x = bf2f(u.x); v.y = bf2f(u.y); v.z = bf2f(u.z); v.w = bf2f(u.w);
  float s  = v.x + v.y + v.z + v.w;
  float ss = v.x * v.x + v.y * v.y + v.z * v.z + v.w * v.w;
#pragma unroll
  for (int o = 32; o > 0; o >>= 1) { s += __shfl_xor(s, o); ss += __shfl_xor(ss, o); }
  __shared__ float red[8];
  int wid = t >> 6, lane = t & 63;
  if (lane == 0) { red[wid] = s; red[4 + wid] = ss; }
  __syncthreads();
  s  = red[0] + red[1] + red[2] + red[3];
  ss = red[4] + red[5] + red[6] + red[7];
  float mean = s * (1.0f / D_);
  float var  = ss * (1.0f / D_) - mean * mean;
  float rs   = rsqrtf(var + 1e-6f);
  const float4 g4 = ((const float4*)G)[t];
  const float4 b4 = ((const float4*)Bv)[t];
  ushort4 pk;
  pk.x = f2bfu((v.x - mean) * rs * g4.x + b4.x);
  pk.y = f2bfu((v.y - mean) * rs * g4.y + b4.y);
  pk.z = f2bfu((v.z - mean) * rs * g4.z + b4.z);
  pk.w = f2bfu((v.w - mean) * rs * g4.w + b4.w);
  ((ushort4*)out)[(size_t)row * (D_ / 4) + t] = pk;
}

enum { EPI_QKV = 0, EPI_BIAS_RES_BF16 = 1, EPI_BIAS_GELU_BF16 = 2, EPI_BIAS_RESB_F32 = 3 };

#define MFMA_ __builtin_amdgcn_mfma_f32_16x16x32_bf16

// ============ 4-wave qkv GEMM: 256x256 tile, per-wave 128x128 ==============
// Rationale: 8-wave 2x4 is LDS-read bound (192 b128 vs 621cy MFMA per K-tile
// -> MfmaUtil 38%). 2x2 waves with 128x128/wave cut reads to 128 b128 per
// K-tile (ratio 2.67->4.0 MFMA/b128) and need only ONE barrier per K-tile.
// acc = 256 VGPR/lane -> 1 wave/SIMD (launch_bounds(256,1)).
__global__ __launch_bounds__(256, 1)
void gemm256q4(const bf16* __restrict__ A, const bf16* __restrict__ Bt,
               bf16* __restrict__ Cq, bf16* __restrict__ Ck, bf16* __restrict__ Cv,
               int M, int N, int K)
{
  extern __shared__ __align__(16) char smem[];
  bf16* lds = (bf16*)smem;

  const int t = threadIdx.x;            // 0..255
  const int wid = t >> 6, lane = t & 63;
  const int wr = wid >> 1, wc = wid & 1;   // 2 x 2 waves
  // same 2D-chunk XCD swizzle (grid 768, nty=64, ntx=12)
  const int bid = blockIdx.x;
  const int c = bid & 7;
  const int w = bid >> 3;
  const int sst = w >> 4;
  const int ii = w & 15;
  const int txg = sst >> 1, tyg = sst & 1;
  const int iy = ii & 3, ix = ii >> 2;
  const int ty = c * 8 + tyg * 4 + iy;
  const int tx = txg * 4 + ix;
  const int m0 = ty << 8, n0 = tx << 8;

  const bf16* Ab = A + (size_t)m0 * K;
  const bf16* Bb = Bt + (size_t)n0 * K;

  const int NT = K >> 6;                // 16
  const int fr = lane & 15;
  const int fksw = (((lane >> 4) ^ ((lane >> 1) & 3)) * 8);
  // staging (256 threads): per (mat,kh) 4 loads; src row = i*64 + (t>>2),
  // col-block (t&3)^((t>>3)&3)  [same involution as read side]
  const int srow = t >> 2;
  const int scol = (((t & 3) ^ ((t >> 3) & 3)) * 8);

  f32x4 acc[8][8] = {};

  #define LDSHALF(b, mat, kh) (lds + (((((b) << 1) + (mat)) << 1) + (kh)) * 8192)
  #define STAGEQ(bkt, akt, mat, kh) do {                                       \
    bf16* _dst = LDSHALF((bkt) & 1, (mat), (kh)) + t * 8;                      \
    const bf16* _sb = ((mat) == 0 ? Ab : Bb) + (size_t)srow * K                \
                      + ((akt) << 6) + (kh) * 32 + scol;                       \
    gload_lds16(_sb,                    _dst);                                 \
    gload_lds16(_sb + (size_t)64 * K,   _dst + 2048);                          \
    gload_lds16(_sb + (size_t)128 * K,  _dst + 4096);                          \
    gload_lds16(_sb + (size_t)192 * K,  _dst + 6144);                          \
  } while (0)

  // prologue
  STAGEQ(0, 0, 0, 0); STAGEQ(0, 0, 1, 0); STAGEQ(0, 0, 0, 1); STAGEQ(0, 0, 1, 1);
  asm volatile("s_waitcnt vmcnt(0)" ::: "memory");
  __builtin_amdgcn_s_barrier();

  for (int kt = 0; kt < NT; ++kt) {
    const int cur = kt & 1;
    const int nk = (kt + 1 < NT) ? (kt + 1) : (NT - 1);  // phantom = last (L2-hot)
    // issue next tile's staging first (hides under MFMA below)
    STAGEQ(kt + 1, nk, 0, 0); STAGEQ(kt + 1, nk, 1, 0);
    STAGEQ(kt + 1, nk, 0, 1); STAGEQ(kt + 1, nk, 1, 1);
#pragma unroll
    for (int kh = 0; kh < 2; ++kh) {
      const bf16* hA = LDSHALF(cur, 0, kh);
      const bf16* hB = LDSHALF(cur, 1, kh);
      bf16x8 a[8], b[8];
#pragma unroll
      for (int mi = 0; mi < 8; ++mi)
        a[mi] = *(const bf16x8*)&hA[(wr * 128 + mi * 16 + fr) * 32 + fksw];
#pragma unroll
      for (int ni = 0; ni < 8; ++ni)
        b[ni] = *(const bf16x8*)&hB[(wc * 128 + ni * 16 + fr) * 32 + fksw];
      __builtin_amdgcn_s_setprio(1);
#pragma unroll
      for (int mi = 0; mi < 8; ++mi)
#pragma unroll
        for (int ni = 0; ni < 8; ++ni)
          acc[mi][ni] = MFMA_(a[mi], b[ni], acc[mi][ni], 0, 0, 0);
      __builtin_amdgcn_s_setprio(0);
    }
    asm volatile("s_waitcnt vmcnt(0)" ::: "memory");   // next tile landed
    __builtin_amdgcn_s_barrier();
  }

  // ---- epilogue: q (n0<1024) LDS-repack; k/v direct transposed stores ----
  const int brow = m0 >> 12;
  const int mrow = m0 & 4095;
  if (n0 < 1024) {
    unsigned short* ot = (unsigned short*)lds;
#pragma unroll
    for (int mi = 0; mi < 8; ++mi) {
#pragma unroll
      for (int ni = 0; ni < 8; ++ni) {
#pragma unroll
        for (int j = 0; j < 4; ++j) {
          int row = wr * 128 + mi * 16 + (lane >> 4) * 4 + j;
          int col = wc * 128 + ni * 16 + fr;
          int u = col >> 3;
          int st = (u & ~7) | ((u ^ row) & 7);
          ot[row * 256 + st * 8 + (col & 7)] = f2bfu(acc[mi][ni][j]);
        }
      }
    }
    __syncthreads();
    int sglob = mrow + t;              // thread = row
#pragma unroll 8
    for (int uu = 0; uu < 32; ++uu) {
      int st = (uu & ~7) | ((uu ^ t) & 7);
      bf16x8 v = *(const bf16x8*)&ot[t * 256 + st * 8];
      int hl = uu >> 3, k8 = uu & 7;
      *(bf16x8*)((unsigned short*)Cq +
        (((size_t)(brow * 16 + (n0 >> 6) + hl) * 4096 + sglob) * 64 + k8 * 8)) = v;
    }
  } else {
    int qsel = n0 >> 10;               // 1 = k, 2 = v (block-uniform)
    unsigned short* base = (unsigned short*)(qsel == 1 ? Ck : Cv);
#pragma unroll
    for (int mi = 0; mi < 8; ++mi) {
      int sloc = mrow + wr * 128 + mi * 16 + (lane >> 4) * 4;
#pragma unroll
      for (int ni = 0; ni < 8; ++ni) {
        int col = n0 + wc * 128 + ni * 16 + fr;
        int hh = (col >> 6) & 15;
        int dd = col & 63;
        ushort4 pk;
        pk.x = f2bfu(acc[mi][ni][0]); pk.y = f2bfu(acc[mi][ni][1]);
        pk.z = f2bfu(acc[mi][ni][2]); pk.w = f2bfu(acc[mi][ni][3]);
        *(ushort4*)(base + (((size_t)(brow * 16 + hh) * 64 + dd) * 4096 + sloc)) = pk;
      }
    }
  }
  #undef STAGEQ
  #undef LDSHALF
}

// ============ 8-wave GEMM (proven r5-r10) for Wo / W1 / W2 =================
template<int EPI, bool AHM>
__global__ __launch_bounds__(512)
void gemm256(const bf16* __restrict__ A, const bf16* __restrict__ Bt,
             float* __restrict__ Cf, bf16* __restrict__ Cb,
             const float* __restrict__ bias, const float* __restrict__ resf,
             const bf16* __restrict__ resb, int M, int N, int K)
{
  extern __shared__ __align__(16) char smem[];
  bf16* lds = (bf16*)smem;

  const int t = threadIdx.x;
  const int wid = t >> 6, lane = t & 63;
  const int wr = wid >> 2, wc = wid & 3;
  const int bid = blockIdx.x;
  const int c = bid & 7;
  const int w = bid >> 3;
  const int sst = w >> 4;
  const int ii = w & 15;
  const int txg = sst >> 1, tyg = sst & 1;
  const int iy = ii & 3, ix = ii >> 2;
  const int ty = c * 8 + tyg * 4 + iy;
  const int tx = txg * 4 + ix;
  const int m0 = ty << 8, n0 = tx << 8;

  const bf16* Ab = AHM
      ? A + (((size_t)(m0 >> 12) * 16) * 4096 + (m0 & 4095)) * 64
      : A + (size_t)m0 * K;
  const bf16* Bb = Bt + (size_t)n0 * K;

  const int srow = t >> 2;
  const int scol = (((t & 3) ^ ((t >> 3) & 3)) * 8);
  const int NT = K >> 6;
  const int fr = lane & 15;
  const int fksw = (((lane >> 4) ^ ((lane >> 1) & 3)) * 8);

  f32x4 acc[8][4] = {};

  #define LDSHALF(b, mat, kh) (lds + (((((b) << 1) + (mat)) << 1) + (kh)) * 8192)
  #define STAGE(bkt, akt, mat, kh) do {                                        \
    bf16* _dst = LDSHALF((bkt) & 1, (mat), (kh)) + t * 8;                      \
    const int _ktk = (akt);                                                    \
    if ((mat) == 0 && AHM) {                                                   \
      const bf16* _sb = Ab + (size_t)_ktk * 262144 + (size_t)srow * 64         \
                        + (kh) * 32 + scol;                                    \
      gload_lds16(_sb, _dst);                                                  \
      gload_lds16(_sb + 8192, _dst + 4096);                                    \
    } else {                                                                   \
      const bf16* _sb = ((mat) == 0 ? Ab : Bb) + (size_t)srow * K              \
                        + (_ktk << 6) + (kh) * 32 + scol;                      \
      gload_lds16(_sb, _dst);                                                  \
      gload_lds16(_sb + (size_t)128 * K, _dst + 4096);                         \
    }                                                                          \
  } while (0)

  STAGE(0, 0, 0, 0); STAGE(0, 0, 1, 0);
  STAGE(0, 0, 0, 1); STAGE(0, 0, 1, 1);
  asm volatile("s_waitcnt vmcnt(4)" ::: "memory");
  __builtin_amdgcn_s_barrier();

#pragma unroll 2
  for (int kt = 0; kt < NT; ++kt) {
    const int cur = kt & 1;
    const int nk = (kt + 1 < NT) ? (kt + 1) : (NT - 1);
    const bf16* hA0 = LDSHALF(cur, 0, 0);
    const bf16* hB0 = LDSHALF(cur, 1, 0);
    const bf16* hA1 = LDSHALF(cur, 0, 1);
    const bf16* hB1 = LDSHALF(cur, 1, 1);
    bf16x8 a[8], b0, b1, b2, b3;

#pragma unroll
    for (int mi = 0; mi < 8; ++mi)
      a[mi] = *(const bf16x8*)&hA0[(wr * 128 + mi * 16 + fr) * 32 + fksw];
    b0 = *(const bf16x8*)&hB0[(wc * 64 +  0 + fr) * 32 + fksw];
    b1 = *(const bf16x8*)&hB0[(wc * 64 + 16 + fr) * 32 + fksw];
    STAGE(kt + 1, nk, 0, 0);
    __builtin_amdgcn_s_barrier();
    __builtin_amdgcn_s_setprio(1);
#pragma unroll
    for (int mi = 0; mi < 8; ++mi) {
      acc[mi][0] = MFMA_(a[mi], b0, acc[mi][0], 0, 0, 0);
      acc[mi][1] = MFMA_(a[mi], b1, acc[mi][1], 0, 0, 0);
    }
    __builtin_amdgcn_s_setprio(0);
    __builtin_amdgcn_s_barrier();

    b2 = *(const bf16x8*)&hB0[(wc * 64 + 32 + fr) * 32 + fksw];
    b3 = *(const bf16x8*)&hB0[(wc * 64 + 48 + fr) * 32 + fksw];
    STAGE(kt + 1, nk, 1, 0);
    __builtin_amdgcn_s_barrier();
    __builtin_amdgcn_s_setprio(1);
#pragma unroll
    for (int mi = 0; mi < 8; ++mi) {
      acc[mi][2] = MFMA_(a[mi], b2, acc[mi][2], 0, 0, 0);
      acc[mi][3] = MFMA_(a[mi], b3, acc[mi][3], 0, 0, 0);
    }
    __builtin_amdgcn_s_setprio(0);
    asm volatile("s_waitcnt vmcnt(4)" ::: "memory");
    __builtin_amdgcn_s_barrier();

#pragma unroll
    for (int mi = 0; mi < 8; ++mi)
      a[mi] = *(const bf16x8*)&hA1[(wr * 128 + mi * 16 + fr) * 32 + fksw];
    b0 = *(const bf16x8*)&hB1[(wc * 64 +  0 + fr) * 32 + fksw];
    b1 = *(const bf16x8*)&hB1[(wc * 64 + 16 + fr) * 32 + fksw];
    STAGE(kt + 1, nk, 0, 1);
    __builtin_amdgcn_s_barrier();
    __builtin_amdgcn_s_setprio(1);
#pragma unroll
    for (int mi = 0; mi < 8; ++mi) {
      acc[mi][0] = MFMA_(a[mi], b0, acc[mi][0], 0, 0, 0);
      acc[mi][1] = MFMA_(a[mi], b1, acc[mi][1], 0, 0, 0);
    }
    __builtin_amdgcn_s_setprio(0);
    __builtin_amdgcn_s_barrier();

    b2 = *(const bf16x8*)&hB1[(wc * 64 + 32 + fr) * 32 + fksw];
    b3 = *(const bf16x8*)&hB1[(wc * 64 + 48 + fr) * 32 + fksw];
    STAGE(kt + 1, nk, 1, 1);
    __builtin_amdgcn_s_barrier();
    __builtin_amdgcn_s_setprio(1);
#pragma unroll
    for (int mi = 0; mi < 8; ++mi) {
      acc[mi][2] = MFMA_(a[mi], b2, acc[mi][2], 0, 0, 0);
      acc[mi][3] = MFMA_(a[mi], b3, acc[mi][3], 0, 0, 0);
    }
    __builtin_amdgcn_s_setprio(0);
    asm volatile("s_waitcnt vmcnt(4)" ::: "memory");
    __builtin_amdgcn_s_barrier();
  }
  asm volatile("s_waitcnt vmcnt(0)" ::: "memory");

  // ---- epilogue (LDS repack, coalesced) ----
  unsigned short* ot = (unsigned short*)lds;
#pragma unroll
  for (int mi = 0; mi < 8; ++mi) {
#pragma unroll
    for (int ni = 0; ni < 4; ++ni) {
#pragma unroll
      for (int j = 0; j < 4; ++j) {
        int row = wr * 128 + mi * 16 + (lane >> 4) * 4 + j;
        int col = wc * 64 + ni * 16 + fr;
        int u = col >> 3;
        int st = (u & ~7) | ((u ^ row) & 7);
        ot[row * 256 + st * 8 + (col & 7)] = f2bfu(acc[mi][ni][j]);
      }
    }
  }
  __syncthreads();

  int rlane = lane & 31;
  int rrow0 = lane >> 5;
  float bias8[8];
  *(float4*)&bias8[0] = *(const float4*)&bias[n0 + rlane * 8];
  *(float4*)&bias8[4] = *(const float4*)&bias[n0 + rlane * 8 + 4];
#pragma unroll 4
  for (int it = 0; it < 16; ++it) {
    int row = wid * 32 + it * 2 + rrow0;
    int st = (rlane & ~7) | ((rlane ^ row) & 7);
    bf16x8 v8 = *(const bf16x8*)&ot[row * 256 + st * 8];
    int grow = m0 + row;
    float o[8];
#pragma unroll
    for (int q = 0; q < 8; ++q) o[q] = bf2f(v8[q]) + bias8[q];
    if (EPI == EPI_BIAS_RES_BF16) {
      const float* rp = resf + (size_t)grow * N + n0 + rlane * 8;
      float4 r0 = *(const float4*)rp, r1 = *(const float4*)(rp + 4);
      o[0] += r0.x; o[1] += r0.y; o[2] += r0.z; o[3] += r0.w;
      o[4] += r1.x; o[5] += r1.y; o[6] += r1.z; o[7] += r1.w;
      bf16x8 wv;
#pragma unroll
      for (int q = 0; q < 8; ++q) wv[q] = (short)f2bfu(o[q]);
      *(bf16x8*)((unsigned short*)Cb + (size_t)grow * N + n0 + rlane * 8) = wv;
    } else if (EPI == EPI_BIAS_GELU_BF16) {
      bf16x8 wv;
#pragma unroll
      for (int q = 0; q < 8; ++q) {
        float u = o[q];
        u = 0.5f * u * (1.0f + erff(u * 0.70710678118654752f));
        wv[q] = (short)f2bfu(u);
      }
      *(bf16x8*)((unsigned short*)Cb + (size_t)grow * N + n0 + rlane * 8) = wv;
    } else {   // EPI_BIAS_RESB_F32
      const unsigned short* rp = (const unsigned short*)resb + (size_t)grow * N + n0 + rlane * 8;
      bf16x8 r8 = *(const bf16x8*)rp;
#pragma unroll
      for (int q = 0; q < 8; ++q) o[q] += bf2f(r8[q]);
      float4 s0, s1;
      s0.x = o[0]; s0.y = o[1]; s0.z = o[2]; s0.w = o[3];
      s1.x = o[4]; s1.y = o[5]; s1.z = o[6]; s1.w = o[7];
      float* op = Cf + (size_t)grow * N + n0 + rlane * 8;
      *(float4*)op = s0;
      *(float4*)(op + 4) = s1;
    }
  }
  #undef STAGE
  #undef LDSHALF
}

// ---------------- ctx split-K partial: MFMA, den fused in-loop -------------
__global__ __launch_bounds__(256)
void ctx_partial(const bf16* __restrict__ kT, const bf16* __restrict__ vT,
                 float* __restrict__ pctx, float* __restrict__ pden)
{
  int blk = blockIdx.x;          // bh*8 + kc
  int kc = blk & 7, bh = blk >> 3;
  int t = threadIdx.x, lane = t & 63, wid = t >> 6;
  const int fr = lane & 15, g = lane >> 4;
  __shared__ float part[4][4096];
  __shared__ float dpart[4][64];

  f32x4 acc[4][4] = {};
  float dsum[4] = {0.f, 0.f, 0.f, 0.f};
  const unsigned short* kb = (const unsigned short*)kT + (size_t)bh * 64 * 4096;
  const unsigned short* vb = (const unsigned short*)vT + (size_t)bh * 64 * 4096;
  const int kbase = kc * 512 + wid * 128;
#pragma unroll
  for (int i = 0; i < 4; ++i) {
    int kofs = kbase + i * 32 + g * 8;
    bf16x8 av[4], bv[4];
#pragma unroll
    for (int mi = 0; mi < 4; ++mi) {
      bf16x8 kr = *(const bf16x8*)(kb + (size_t)(mi * 16 + fr) * 4096 + kofs);
      bf16x8 ae;
      float es = 0.f;
#pragma unroll
      for (int j = 0; j < 8; ++j) {
        float e = __expf(bf2f(kr[j]));
        es += e;
        ae[j] = (short)f2bfu(e);
      }
      dsum[mi] += es;
      av[mi] = ae;
      bv[mi] = *(const bf16x8*)(vb + (size_t)(mi * 16 + fr) * 4096 + kofs);
    }
#pragma unroll
    for (int mi = 0; mi < 4; ++mi)
#pragma unroll
      for (int ni = 0; ni < 4; ++ni)
        acc[mi][ni] = MFMA_(av[mi], bv[ni], acc[mi][ni], 0, 0, 0);
  }
#pragma unroll
  for (int mi = 0; mi < 4; ++mi) {
    dsum[mi] += __shfl_xor(dsum[mi], 16);
    dsum[mi] += __shfl_xor(dsum[mi], 32);
  }
#pragma unroll
  for (int mi = 0; mi < 4; ++mi)
#pragma unroll
    for (int ni = 0; ni < 4; ++ni)
      *(f32x4*)&part[wid][(mi * 4 + ni) * 256 + lane * 4] = acc[mi][ni];
  if (g == 0) {
#pragma unroll
    for (int mi = 0; mi < 4; ++mi) dpart[wid][mi * 16 + fr] = dsum[mi];
  }
  __syncthreads();
  int lane2 = t & 63, fg = t >> 6;
#pragma unroll
  for (int ff = 0; ff < 4; ++ff) {
    int f = fg * 4 + ff;
    f32x4 s = {};
#pragma unroll
    for (int ww = 0; ww < 4; ++ww)
      s += *(const f32x4*)&part[ww][f * 256 + lane2 * 4];
    *(f32x4*)&pctx[((size_t)blk * 16 + f) * 256 + lane2 * 4] = s;
  }
  if (t < 64)
    pden[blk * 64 + t] = dpart[0][t] + dpart[1][t] + dpart[2][t] + dpart[3][t];
}

// ---------------- ctx merge: sum 8 k-slices, normalize, emit bf16 ctxT -----
__global__ __launch_bounds__(256)
void ctx_merge(const float* __restrict__ pctx, const float* __restrict__ pden,
               bf16* __restrict__ ctxT)
{
  int bh = blockIdx.x;
  int t = threadIdx.x, lane2 = t & 63, fg = t >> 6;
  __shared__ float rden[64];
  if (t < 64) {
    float s = 0.f;
    for (int kc = 0; kc < 8; ++kc) s += pden[(bh * 8 + kc) * 64 + t];
    rden[t] = 1.0f / s;
  }
  __syncthreads();
  int fr2 = lane2 & 15, g2 = lane2 >> 4;
#pragma unroll
  for (int ff = 0; ff < 4; ++ff) {
    int f = fg * 4 + ff;
    int mi = f >> 2, ni = f & 3;
    f32x4 s = {};
#pragma unroll
    for (int kc = 0; kc < 8; ++kc)
      s += *(const f32x4*)&pctx[(((size_t)(bh * 8 + kc)) * 16 + f) * 256 + lane2 * 4];
    int e = ni * 16 + fr2;
    int d0 = mi * 16 + g2 * 4;
    ushort4 pk;
    pk.x = f2bfu(s[0] * rden[d0 + 0]);
    pk.y = f2bfu(s[1] * rden[d0 + 1]);
    pk.z = f2bfu(s[2] * rden[d0 + 2]);
    pk.w = f2bfu(s[3] * rden[d0 + 3]);
    *(ushort4*)((unsigned short*)ctxT + ((size_t)bh * 64 + e) * 64 + d0) = pk;
  }
}

// ---------------- attn: softmax(q)*DH^-.5 @ ctx -> attn_hm, MFMA -----------
__global__ __launch_bounds__(256)
void attn_kernel(const bf16* __restrict__ qhm, const bf16* __restrict__ ctxT,
                 bf16* __restrict__ attn)
{
  int blk = blockIdx.x;           // bh*16 + chunk
  int chunk = blk & 15, bh = blk >> 4;
  int t = threadIdx.x, lane = t & 63, wid = t >> 6;
  __shared__ bf16 P[256 * 64];
  __shared__ bf16 CT[64 * 64];

  {
    const unsigned short* cg = (const unsigned short*)ctxT + (size_t)bh * 4096;
#pragma unroll
    for (int r = 0; r < 2; ++r) {
      int idx = r * 256 + t;
      int e = idx >> 3, b = idx & 7;
      bf16x8 v = *(const bf16x8*)(cg + idx * 8);
      *(bf16x8*)&CT[e * 64 + ((b ^ (e & 7)) * 8)] = v;
    }
  }
  {
    int s = chunk * 256 + t;
    const unsigned short* qp = (const unsigned short*)qhm + ((size_t)bh * 4096 + s) * 64;
    float p[64];
#pragma unroll
    for (int j = 0; j < 8; ++j) {
      bf16x8 q8 = *(const bf16x8*)(qp + j * 8);
#pragma unroll
      for (int i = 0; i < 8; ++i) p[j * 8 + i] = bf2f(q8[i]);
    }
    float mx = p[0];
#pragma unroll
    for (int d = 1; d < 64; ++d) mx = fmaxf(mx, p[d]);
    float sum = 0.f;
#pragma unroll
    for (int d = 0; d < 64; ++d) { p[d] = __expf(p[d] - mx); sum += p[d]; }
    float f = 0.125f / sum;       // DH^-0.5
    bf16* pb = &P[(t >> 6) * 4096 + (t & 63) * 64];
#pragma unroll
    for (int b = 0; b < 8; ++b) {
      bf16x8 pk;
#pragma unroll
      for (int i = 0; i < 8; ++i) pk[i] = (short)f2bfu(p[b * 8 + i] * f);
      *(bf16x8*)&pb[((b ^ (t & 7)) * 8)] = pk;
    }
  }
  __syncthreads();

  const int fr = lane & 15, g = lane >> 4;
  f32x4 acc[4][4] = {};
  const bf16* Pw = &P[wid * 4096];
#pragma unroll
  for (int ks = 0; ks < 2; ++ks) {
    bf16x8 av[4], bv[4];
#pragma unroll
    for (int mi = 0; mi < 4; ++mi) {
      int r = mi * 16 + fr;
      av[mi] = *(const bf16x8*)&Pw[r * 64 + (((ks * 4 + g) ^ (r & 7)) * 8)];
    }
#pragma unroll
    for (int ni = 0; ni < 4; ++ni) {
      int e = ni * 16 + fr;
      bv[ni] = *(const bf16x8*)&CT[e * 64 + (((ks * 4 + g) ^ (e & 7)) * 8)];
    }
#pragma unroll
    for (int mi = 0; mi < 4; ++mi)
#pragma unroll
      for (int ni = 0; ni < 4; ++ni)
        acc[mi][ni] = MFMA_(av[mi], bv[ni], acc[mi][ni], 0, 0, 0);
  }
  unsigned short* ob = (unsigned short*)attn +
      ((size_t)bh * 4096 + chunk * 256 + wid * 64) * 64;
#pragma unroll
  for (int mi = 0; mi < 4; ++mi)
#pragma unroll
    for (int ni = 0; ni < 4; ++ni) {
      int e = ni * 16 + fr;
#pragma unroll
      for (int j = 0; j < 4; ++j) {
        int r = mi * 16 + g * 4 + j;
        ob[(size_t)r * 64 + e] = f2bfu(acc[mi][ni][j]);
      }
    }
}

// ---------------- ws layout (bytes) — total 160 MiB -------------------------
#define OFF_WQKVT  ((size_t)0)
#define OFF_WOT    ((size_t)6291456)
#define OFF_W1T    ((size_t)8388608)
#define OFF_W2T    ((size_t)10485760)
#define OFF_CTXT   ((size_t)12582912)
#define OFF_PCTX   ((size_t)13631488)
#define OFF_PDEN   ((size_t)22020096)
#define OFF_ATTN   ((size_t)33554432)
#define OFF_H      OFF_ATTN
#define OFF_QHM    ((size_t)67108864)
#define OFF_KT     ((size_t)100663296)
#define OFF_VT     ((size_t)134217728)
#define OFF_Z      OFF_QHM
#define OFF_X2B    OFF_KT
#define OFF_Y      OFF_VT

extern "C" void kernel_launch(void* const* d_in, const int* in_sizes, int n_in,
                              void* d_out, int out_size, void* d_ws, size_t ws_size,
                              hipStream_t stream)
{
  const float* x     = (const float*)d_in[0];
  const float* ln1_g = (const float*)d_in[1];
  const float* ln1_b = (const float*)d_in[2];
  const float* Wqkv  = (const float*)d_in[3];
  const float* Wo    = (const float*)d_in[4];
  const float* bo    = (const float*)d_in[5];
  const float* ln2_g = (const float*)d_in[6];
  const float* ln2_b = (const float*)d_in[7];
  const float* W1    = (const float*)d_in[8];
  const float* b1    = (const float*)d_in[9];
  const float* W2    = (const float*)d_in[10];
  const float* b2    = (const float*)d_in[11];
  float* out = (float*)d_out;
  char* ws = (char*)d_ws;

  bf16*  h     = (bf16*)(ws + OFF_H);
  bf16*  attn  = (bf16*)(ws + OFF_ATTN);
  bf16*  qhm   = (bf16*)(ws + OFF_QHM);
  bf16*  kT    = (bf16*)(ws + OFF_KT);
  bf16*  vT    = (bf16*)(ws + OFF_VT);
  bf16*  ctxT  = (bf16*)(ws + OFF_CTXT);
  float* pctx  = (float*)(ws + OFF_PCTX);
  float* pden  = (float*)(ws + OFF_PDEN);
  bf16*  x2b   = (bf16*)(ws + OFF_X2B);
  bf16*  y     = (bf16*)(ws + OFF_Y);
  bf16*  z     = (bf16*)(ws + OFF_Z);
  bf16*  wqkvt = (bf16*)(ws + OFF_WQKVT);
  bf16*  wot   = (bf16*)(ws + OFF_WOT);
  bf16*  w1t   = (bf16*)(ws + OFF_W1T);
  bf16*  w2t   = (bf16*)(ws + OFF_W2T);

  const size_t GEMM_LDS = 131072;

  prep_kernel<<<BS_ + 192 * 32, 256, 0, stream>>>(
      x, ln1_g, ln1_b, h, Wqkv, Wo, W1, W2, wqkvt, wot, w1t, w2t);

  // qkv gemm: 4-wave 128x128-per-wave variant
  gemm256q4<<<(N3_ / 256) * (BS_ / 256), 256, GEMM_LDS, stream>>>(
      h, wqkvt, qhm, kT, vT, BS_, N3_, D_);

  ctx_partial<<<512, 256, 0, stream>>>(kT, vT, pctx, pden);
  ctx_merge<<<64, 256, 0, stream>>>(pctx, pden, ctxT);

  attn_kernel<<<1024, 256, 0, stream>>>(qhm, ctxT, attn);

  gemm256<EPI_BIAS_RES_BF16, true><<<(D_ / 256) * (BS_ / 256), 512, GEMM_LDS, stream>>>(
      attn, wot, nullptr, x2b, bo, x, nullptr, BS_, D_, D_);

  ln_kernel<<<BS_, 256, 0, stream>>>(x2b, ln2_g, ln2_b, y);

  gemm256<EPI_BIAS_GELU_BF16, false><<<(D_ / 256) * (BS_ / 256), 512, GEMM_LDS, stream>>>(
      y, w1t, nullptr, z, b1, nullptr, nullptr, BS_, D_, D_);

  gemm256<EPI_BIAS_RESB_F32, false><<<(D_ / 256) * (BS_ / 256), 512, GEMM_LDS, stream>>>(
      z, w2t, out, nullptr, b2, nullptr, x2b, BS_, D_, D_);
}

// Round 12
// 356.778 us; speedup vs baseline: 1.0571x; 1.0571x over previous
//
#include <hip/hip_runtime.h>
#include <hip/hip_bf16.h>
#include <math.h>

#define B_   4
#define S_   4096
#define D_   1024
#define H_   16
#define DH_  64
#define BS_  (B_ * S_)     // 16384 rows
#define N3_  3072          // 3 * INNER

using bf16 = __hip_bfloat16;
typedef __attribute__((ext_vector_type(8))) short bf16x8;
typedef __attribute__((ext_vector_type(4))) float f32x4;

#define GAS __attribute__((address_space(1)))
#define LAS __attribute__((address_space(3)))

__device__ __forceinline__ void gload_lds16(const bf16* g, bf16* l) {
  __builtin_amdgcn_global_load_lds((const GAS void*)g, (LAS void*)l, 16, 0, 0);
}

__device__ __forceinline__ float bf2f(short u) {
  unsigned int x = ((unsigned int)(unsigned short)u) << 16;
  return __builtin_bit_cast(float, x);
}
__device__ __forceinline__ unsigned short f2bfu(float f) {
  bf16 t = __float2bfloat16(f);
  return *(unsigned short*)&t;
}

// ------------- fused prep: LN1(+PE) AND 4x weight transpose, one launch ----
__global__ __launch_bounds__(256)
void prep_kernel(const float* __restrict__ x, const float* __restrict__ ln1_g,
                 const float* __restrict__ ln1_b, bf16* __restrict__ h,
                 const float* __restrict__ Wqkv, const float* __restrict__ Wo,
                 const float* __restrict__ W1, const float* __restrict__ W2,
                 bf16* __restrict__ wqkvt, bf16* __restrict__ wot,
                 bf16* __restrict__ w1t, bf16* __restrict__ w2t)
{
  int bid = blockIdx.x;
  int t = threadIdx.x;
  if (bid < BS_) {
    int row = bid;
    float4 v = ((const float4*)(x + (size_t)row * D_))[t];
    float s  = v.x + v.y + v.z + v.w;
    float ss = v.x * v.x + v.y * v.y + v.z * v.z + v.w * v.w;
#pragma unroll
    for (int o = 32; o > 0; o >>= 1) { s += __shfl_xor(s, o); ss += __shfl_xor(ss, o); }
    __shared__ float red[8];
    int wid = t >> 6, lane = t & 63;
    if (lane == 0) { red[wid] = s; red[4 + wid] = ss; }
    __syncthreads();
    s  = red[0] + red[1] + red[2] + red[3];
    ss = red[4] + red[5] + red[6] + red[7];
    float mean = s * (1.0f / D_);
    float var  = ss * (1.0f / D_) - mean * mean;
    float rs   = rsqrtf(var + 1e-6f);
    int d0 = t * 4;
    const float4 g4 = ((const float4*)ln1_g)[t];
    const float4 b4 = ((const float4*)ln1_b)[t];
    float o0 = (v.x - mean) * rs * g4.x + b4.x;
    float o1 = (v.y - mean) * rs * g4.y + b4.y;
    float o2 = (v.z - mean) * rs * g4.z + b4.z;
    float o3 = (v.w - mean) * rs * g4.w + b4.w;
    const float C = -0.0089944730194f;   // -ln(10000)/1024
    float p = (float)(row & (S_ - 1));
    float sn, cs;
    __sincosf(p * __expf((float)d0 * C), &sn, &cs);        o0 += sn; o1 += cs;
    __sincosf(p * __expf((float)(d0 + 2) * C), &sn, &cs);  o2 += sn; o3 += cs;
    ushort4 pk;
    pk.x = f2bfu(o0); pk.y = f2bfu(o1); pk.z = f2bfu(o2); pk.w = f2bfu(o3);
    ((ushort4*)h)[(size_t)row * (D_ / 4) + t] = pk;
  } else {
    int e = bid - BS_;
    int gx = e % 192, ky = e / 192;
    __shared__ float tile[32][33];
    const float* W; bf16* Wt; int N, xo;
    if (gx < 96)        { W = Wqkv; Wt = wqkvt; N = N3_; xo = gx; }
    else if (gx < 128)  { W = Wo;   Wt = wot;   N = D_;  xo = gx - 96; }
    else if (gx < 160)  { W = W1;   Wt = w1t;   N = D_;  xo = gx - 128; }
    else                { W = W2;   Wt = w2t;   N = D_;  xo = gx - 160; }
    int n0 = xo * 32, k0 = ky * 32;
    int tx = t & 31, ty = t >> 5;
#pragma unroll
    for (int j = 0; j < 32; j += 8)
      tile[ty + j][tx] = W[(size_t)(k0 + ty + j) * N + n0 + tx];
    __syncthreads();
#pragma unroll
    for (int j = 0; j < 32; j += 8)
      Wt[(size_t)(n0 + ty + j) * 1024 + k0 + tx] = __float2bfloat16(tile[tx][ty + j]);
  }
}

// ---------------- LayerNorm bf16-in -> bf16 (LN2) --------------------------
__global__ __launch_bounds__(256)
void ln_kernel(const bf16* __restrict__ Xb, const float* __restrict__ G,
               const float* __restrict__ Bv, bf16* __restrict__ out)
{
  int row = blockIdx.x;
  int t = threadIdx.x;
  ushort4 u = ((const ushort4*)Xb)[(size_t)row * (D_ / 4) + t];
  float4 v;
  v.x = bf2f(u.x); v.y = bf2f(u.y); v.z = bf2f(u.z); v.w = bf2f(u.w);
  float s  = v.x + v.y + v.z + v.w;
  float ss = v.x * v.x + v.y * v.y + v.z * v.z + v.w * v.w;
#pragma unroll
  for (int o = 32; o > 0; o >>= 1) { s += __shfl_xor(s, o); ss += __shfl_xor(ss, o); }
  __shared__ float red[8];
  int wid = t >> 6, lane = t & 63;
  if (lane == 0) { red[wid] = s; red[4 + wid] = ss; }
  __syncthreads();
  s  = red[0] + red[1] + red[2] + red[3];
  ss = red[4] + red[5] + red[6] + red[7];
  float mean = s * (1.0f / D_);
  float var  = ss * (1.0f / D_) - mean * mean;
  float rs   = rsqrtf(var + 1e-6f);
  const float4 g4 = ((const float4*)G)[t];
  const float4 b4 = ((const float4*)Bv)[t];
  ushort4 pk;
  pk.x = f2bfu((v.x - mean) * rs * g4.x + b4.x);
  pk.y = f2bfu((v.y - mean) * rs * g4.y + b4.y);
  pk.z = f2bfu((v.z - mean) * rs * g4.z + b4.z);
  pk.w = f2bfu((v.w - mean) * rs * g4.w + b4.w);
  ((ushort4*)out)[(size_t)row * (D_ / 4) + t] = pk;
}

// ---------------- 256x256 8-phase bf16 MFMA GEMM (proven r5-r10) -----------
enum { EPI_QKV = 0, EPI_BIAS_RES_BF16 = 1, EPI_BIAS_GELU_BF16 = 2, EPI_BIAS_RESB_F32 = 3 };

#define MFMA_ __builtin_amdgcn_mfma_f32_16x16x32_bf16

template<int EPI, bool AHM>
__global__ __launch_bounds__(512)
void gemm256(const bf16* __restrict__ A, const bf16* __restrict__ Bt,
             float* __restrict__ Cf, bf16* __restrict__ Cb,
             const float* __restrict__ bias, const float* __restrict__ resf,
             const bf16* __restrict__ resb,
             bf16* __restrict__ Ck, bf16* __restrict__ Cv,
             int M, int N, int K)
{
  extern __shared__ __align__(16) char smem[];
  bf16* lds = (bf16*)smem;

  const int t = threadIdx.x;
  const int wid = t >> 6, lane = t & 63;
  const int wr = wid >> 2, wc = wid & 3;        // 2 x 4 waves
  // XCD-aware 2D-chunked swizzle (nty==64, ntx%4==0, grid%8==0)
  const int bid = blockIdx.x;
  const int c = bid & 7;
  const int w = bid >> 3;
  const int sst = w >> 4;
  const int ii = w & 15;
  const int txg = sst >> 1, tyg = sst & 1;
  const int iy = ii & 3, ix = ii >> 2;
  const int ty = c * 8 + tyg * 4 + iy;
  const int tx = txg * 4 + ix;
  const int m0 = ty << 8, n0 = tx << 8;

  const bf16* Ab = AHM
      ? A + (((size_t)(m0 >> 12) * 16) * 4096 + (m0 & 4095)) * 64
      : A + (size_t)m0 * K;
  const bf16* Bb = Bt + (size_t)n0 * K;

  const int srow = t >> 2;
  const int scol = (((t & 3) ^ ((t >> 3) & 3)) * 8);
  const int NT = K >> 6;
  const int fr = lane & 15;
  const int fksw = (((lane >> 4) ^ ((lane >> 1) & 3)) * 8);

  f32x4 acc[8][4] = {};

  #define LDSHALF(b, mat, kh) (lds + (((((b) << 1) + (mat)) << 1) + (kh)) * 8192)
  #define STAGE(bkt, akt, mat, kh) do {                                        \
    bf16* _dst = LDSHALF((bkt) & 1, (mat), (kh)) + t * 8;                      \
    const int _ktk = (akt);                                                    \
    if ((mat) == 0 && AHM) {                                                   \
      const bf16* _sb = Ab + (size_t)_ktk * 262144 + (size_t)srow * 64         \
                        + (kh) * 32 + scol;                                    \
      gload_lds16(_sb, _dst);                                                  \
      gload_lds16(_sb + 8192, _dst + 4096);                                    \
    } else {                                                                   \
      const bf16* _sb = ((mat) == 0 ? Ab : Bb) + (size_t)srow * K              \
                        + (_ktk << 6) + (kh) * 32 + scol;                      \
      gload_lds16(_sb, _dst);                                                  \
      gload_lds16(_sb + (size_t)128 * K, _dst + 4096);                         \
    }                                                                          \
  } while (0)

  STAGE(0, 0, 0, 0); STAGE(0, 0, 1, 0);
  STAGE(0, 0, 0, 1); STAGE(0, 0, 1, 1);
  asm volatile("s_waitcnt vmcnt(4)" ::: "memory");
  __builtin_amdgcn_s_barrier();

#pragma unroll 2
  for (int kt = 0; kt < NT; ++kt) {
    const int cur = kt & 1;
    const int nk = (kt + 1 < NT) ? (kt + 1) : (NT - 1);   // phantom = last tile
    const bf16* hA0 = LDSHALF(cur, 0, 0);
    const bf16* hB0 = LDSHALF(cur, 1, 0);
    const bf16* hA1 = LDSHALF(cur, 0, 1);
    const bf16* hB1 = LDSHALF(cur, 1, 1);
    bf16x8 a[8], b0, b1, b2, b3;

    // ---- phase 1 ----
#pragma unroll
    for (int mi = 0; mi < 8; ++mi)
      a[mi] = *(const bf16x8*)&hA0[(wr * 128 + mi * 16 + fr) * 32 + fksw];
    b0 = *(const bf16x8*)&hB0[(wc * 64 +  0 + fr) * 32 + fksw];
    b1 = *(const bf16x8*)&hB0[(wc * 64 + 16 + fr) * 32 + fksw];
    STAGE(kt + 1, nk, 0, 0);
    __builtin_amdgcn_s_barrier();
    __builtin_amdgcn_s_setprio(1);
#pragma unroll
    for (int mi = 0; mi < 8; ++mi) {
      acc[mi][0] = MFMA_(a[mi], b0, acc[mi][0], 0, 0, 0);
      acc[mi][1] = MFMA_(a[mi], b1, acc[mi][1], 0, 0, 0);
    }
    __builtin_amdgcn_s_setprio(0);
    __builtin_amdgcn_s_barrier();

    // ---- phase 2 ----
    b2 = *(const bf16x8*)&hB0[(wc * 64 + 32 + fr) * 32 + fksw];
    b3 = *(const bf16x8*)&hB0[(wc * 64 + 48 + fr) * 32 + fksw];
    STAGE(kt + 1, nk, 1, 0);
    __builtin_amdgcn_s_barrier();
    __builtin_amdgcn_s_setprio(1);
#pragma unroll
    for (int mi = 0; mi < 8; ++mi) {
      acc[mi][2] = MFMA_(a[mi], b2, acc[mi][2], 0, 0, 0);
      acc[mi][3] = MFMA_(a[mi], b3, acc[mi][3], 0, 0, 0);
    }
    __builtin_amdgcn_s_setprio(0);
    asm volatile("s_waitcnt vmcnt(4)" ::: "memory");
    __builtin_amdgcn_s_barrier();

    // ---- phase 3 ----
#pragma unroll
    for (int mi = 0; mi < 8; ++mi)
      a[mi] = *(const bf16x8*)&hA1[(wr * 128 + mi * 16 + fr) * 32 + fksw];
    b0 = *(const bf16x8*)&hB1[(wc * 64 +  0 + fr) * 32 + fksw];
    b1 = *(const bf16x8*)&hB1[(wc * 64 + 16 + fr) * 32 + fksw];
    STAGE(kt + 1, nk, 0, 1);
    __builtin_amdgcn_s_barrier();
    __builtin_amdgcn_s_setprio(1);
#pragma unroll
    for (int mi = 0; mi < 8; ++mi) {
      acc[mi][0] = MFMA_(a[mi], b0, acc[mi][0], 0, 0, 0);
      acc[mi][1] = MFMA_(a[mi], b1, acc[mi][1], 0, 0, 0);
    }
    __builtin_amdgcn_s_setprio(0);
    __builtin_amdgcn_s_barrier();

    // ---- phase 4 ----
    b2 = *(const bf16x8*)&hB1[(wc * 64 + 32 + fr) * 32 + fksw];
    b3 = *(const bf16x8*)&hB1[(wc * 64 + 48 + fr) * 32 + fksw];
    STAGE(kt + 1, nk, 1, 1);
    __builtin_amdgcn_s_barrier();
    __builtin_amdgcn_s_setprio(1);
#pragma unroll
    for (int mi = 0; mi < 8; ++mi) {
      acc[mi][2] = MFMA_(a[mi], b2, acc[mi][2], 0, 0, 0);
      acc[mi][3] = MFMA_(a[mi], b3, acc[mi][3], 0, 0, 0);
    }
    __builtin_amdgcn_s_setprio(0);
    asm volatile("s_waitcnt vmcnt(4)" ::: "memory");
    __builtin_amdgcn_s_barrier();
  }
  asm volatile("s_waitcnt vmcnt(0)" ::: "memory");

  // ======== epilogue ========
  unsigned short* ot = (unsigned short*)lds;   // 256x256 bf16 tile, swizzled units

  const bool q_repack = (EPI == EPI_QKV) && (n0 < 1024);
  if (EPI != EPI_QKV || q_repack) {
#pragma unroll
    for (int mi = 0; mi < 8; ++mi) {
#pragma unroll
      for (int ni = 0; ni < 4; ++ni) {
#pragma unroll
        for (int j = 0; j < 4; ++j) {
          int row = wr * 128 + mi * 16 + (lane >> 4) * 4 + j;
          int col = wc * 64 + ni * 16 + fr;
          int u = col >> 3;
          int st = (u & ~7) | ((u ^ row) & 7);
          ot[row * 256 + st * 8 + (col & 7)] = f2bfu(acc[mi][ni][j]);
        }
      }
    }
    __syncthreads();
  }

  if (EPI == EPI_QKV) {
    const int brow = m0 >> 12;
    const int mrow = m0 & 4095;
    if (q_repack) {
      int tq = t & 3, trow = t >> 2;
#pragma unroll
      for (int p = 0; p < 2; ++p) {
        int row = p * 128 + trow;
        int sglob = mrow + row;
#pragma unroll
        for (int i = 0; i < 8; ++i) {
          int uu = i * 4 + tq;
          int hl = uu >> 3, k = uu & 7;
          int st = (uu & ~7) | ((uu ^ row) & 7);
          bf16x8 v = *(const bf16x8*)&ot[row * 256 + st * 8];
          unsigned short* dst = (unsigned short*)Cb +
            (((size_t)(brow * 16 + (n0 >> 6) + hl) * 4096 + sglob) * 64 + k * 8);
          *(bf16x8*)dst = v;
        }
      }
    } else {
      int qsel = n0 >> 10;
#pragma unroll
      for (int mi = 0; mi < 8; ++mi) {
        int sloc = mrow + wr * 128 + mi * 16 + (lane >> 4) * 4;
#pragma unroll
        for (int ni = 0; ni < 4; ++ni) {
          int col = n0 + wc * 64 + ni * 16 + fr;
          int hh = (col >> 6) & 15;
          int dd = col & 63;
          unsigned short* kp = (unsigned short*)(qsel == 1 ? Ck : Cv) +
            (((size_t)(brow * 16 + hh) * 64 + dd) * 4096 + sloc);
          ushort4 pk;
          pk.x = f2bfu(acc[mi][ni][0]); pk.y = f2bfu(acc[mi][ni][1]);
          pk.z = f2bfu(acc[mi][ni][2]); pk.w = f2bfu(acc[mi][ni][3]);
          *(ushort4*)kp = pk;
        }
      }
    }
  } else {
    int rlane = lane & 31;
    int rrow0 = lane >> 5;
    float bias8[8];
    *(float4*)&bias8[0] = *(const float4*)&bias[n0 + rlane * 8];
    *(float4*)&bias8[4] = *(const float4*)&bias[n0 + rlane * 8 + 4];
#pragma unroll 4
    for (int it = 0; it < 16; ++it) {
      int row = wid * 32 + it * 2 + rrow0;
      int st = (rlane & ~7) | ((rlane ^ row) & 7);
      bf16x8 v8 = *(const bf16x8*)&ot[row * 256 + st * 8];
      int grow = m0 + row;
      float o[8];
#pragma unroll
      for (int q = 0; q < 8; ++q) o[q] = bf2f(v8[q]) + bias8[q];
      if (EPI == EPI_BIAS_RES_BF16) {
        const float* rp = resf + (size_t)grow * N + n0 + rlane * 8;
        float4 r0 = *(const float4*)rp, r1 = *(const float4*)(rp + 4);
        o[0] += r0.x; o[1] += r0.y; o[2] += r0.z; o[3] += r0.w;
        o[4] += r1.x; o[5] += r1.y; o[6] += r1.z; o[7] += r1.w;
        bf16x8 wv;
#pragma unroll
        for (int q = 0; q < 8; ++q) wv[q] = (short)f2bfu(o[q]);
        *(bf16x8*)((unsigned short*)Cb + (size_t)grow * N + n0 + rlane * 8) = wv;
      } else if (EPI == EPI_BIAS_GELU_BF16) {
        bf16x8 wv;
#pragma unroll
        for (int q = 0; q < 8; ++q) {
          float u = o[q];
          u = 0.5f * u * (1.0f + erff(u * 0.70710678118654752f));
          wv[q] = (short)f2bfu(u);
        }
        *(bf16x8*)((unsigned short*)Cb + (size_t)grow * N + n0 + rlane * 8) = wv;
      } else {   // EPI_BIAS_RESB_F32
        const unsigned short* rp = (const unsigned short*)resb + (size_t)grow * N + n0 + rlane * 8;
        bf16x8 r8 = *(const bf16x8*)rp;
#pragma unroll
        for (int q = 0; q < 8; ++q) o[q] += bf2f(r8[q]);
        float4 s0, s1;
        s0.x = o[0]; s0.y = o[1]; s0.z = o[2]; s0.w = o[3];
        s1.x = o[4]; s1.y = o[5]; s1.z = o[6]; s1.w = o[7];
        float* op = Cf + (size_t)grow * N + n0 + rlane * 8;
        *(float4*)op = s0;
        *(float4*)(op + 4) = s1;
      }
    }
  }
  #undef STAGE
  #undef LDSHALF
}

// ---------------- ctx split-K partial: MFMA, den fused in-loop -------------
__global__ __launch_bounds__(256)
void ctx_partial(const bf16* __restrict__ kT, const bf16* __restrict__ vT,
                 float* __restrict__ pctx, float* __restrict__ pden)
{
  int blk = blockIdx.x;          // bh*8 + kc
  int kc = blk & 7, bh = blk >> 3;
  int t = threadIdx.x, lane = t & 63, wid = t >> 6;
  const int fr = lane & 15, g = lane >> 4;
  __shared__ float part[4][4096];
  __shared__ float dpart[4][64];

  f32x4 acc[4][4] = {};
  float dsum[4] = {0.f, 0.f, 0.f, 0.f};
  const unsigned short* kb = (const unsigned short*)kT + (size_t)bh * 64 * 4096;
  const unsigned short* vb = (const unsigned short*)vT + (size_t)bh * 64 * 4096;
  const int kbase = kc * 512 + wid * 128;
#pragma unroll
  for (int i = 0; i < 4; ++i) {
    int kofs = kbase + i * 32 + g * 8;
    bf16x8 av[4], bv[4];
#pragma unroll
    for (int mi = 0; mi < 4; ++mi) {
      bf16x8 kr = *(const bf16x8*)(kb + (size_t)(mi * 16 + fr) * 4096 + kofs);
      bf16x8 ae;
      float es = 0.f;
#pragma unroll
      for (int j = 0; j < 8; ++j) {
        float e = __expf(bf2f(kr[j]));
        es += e;
        ae[j] = (short)f2bfu(e);
      }
      dsum[mi] += es;
      av[mi] = ae;
      bv[mi] = *(const bf16x8*)(vb + (size_t)(mi * 16 + fr) * 4096 + kofs);
    }
#pragma unroll
    for (int mi = 0; mi < 4; ++mi)
#pragma unroll
      for (int ni = 0; ni < 4; ++ni)
        acc[mi][ni] = MFMA_(av[mi], bv[ni], acc[mi][ni], 0, 0, 0);
  }
#pragma unroll
  for (int mi = 0; mi < 4; ++mi) {
    dsum[mi] += __shfl_xor(dsum[mi], 16);
    dsum[mi] += __shfl_xor(dsum[mi], 32);
  }
#pragma unroll
  for (int mi = 0; mi < 4; ++mi)
#pragma unroll
    for (int ni = 0; ni < 4; ++ni)
      *(f32x4*)&part[wid][(mi * 4 + ni) * 256 + lane * 4] = acc[mi][ni];
  if (g == 0) {
#pragma unroll
    for (int mi = 0; mi < 4; ++mi) dpart[wid][mi * 16 + fr] = dsum[mi];
  }
  __syncthreads();
  int lane2 = t & 63, fg = t >> 6;
#pragma unroll
  for (int ff = 0; ff < 4; ++ff) {
    int f = fg * 4 + ff;
    f32x4 s = {};
#pragma unroll
    for (int ww = 0; ww < 4; ++ww)
      s += *(const f32x4*)&part[ww][f * 256 + lane2 * 4];
    *(f32x4*)&pctx[((size_t)blk * 16 + f) * 256 + lane2 * 4] = s;
  }
  if (t < 64)
    pden[blk * 64 + t] = dpart[0][t] + dpart[1][t] + dpart[2][t] + dpart[3][t];
}

// ---------------- ctx merge: sum 8 k-slices, normalize, emit bf16 ctxT -----
__global__ __launch_bounds__(256)
void ctx_merge(const float* __restrict__ pctx, const float* __restrict__ pden,
               bf16* __restrict__ ctxT)
{
  int bh = blockIdx.x;
  int t = threadIdx.x, lane2 = t & 63, fg = t >> 6;
  __shared__ float rden[64];
  if (t < 64) {
    float s = 0.f;
    for (int kc = 0; kc < 8; ++kc) s += pden[(bh * 8 + kc) * 64 + t];
    rden[t] = 1.0f / s;
  }
  __syncthreads();
  int fr2 = lane2 & 15, g2 = lane2 >> 4;
#pragma unroll
  for (int ff = 0; ff < 4; ++ff) {
    int f = fg * 4 + ff;
    int mi = f >> 2, ni = f & 3;
    f32x4 s = {};
#pragma unroll
    for (int kc = 0; kc < 8; ++kc)
      s += *(const f32x4*)&pctx[(((size_t)(bh * 8 + kc)) * 16 + f) * 256 + lane2 * 4];
    int e = ni * 16 + fr2;
    int d0 = mi * 16 + g2 * 4;
    ushort4 pk;
    pk.x = f2bfu(s[0] * rden[d0 + 0]);
    pk.y = f2bfu(s[1] * rden[d0 + 1]);
    pk.z = f2bfu(s[2] * rden[d0 + 2]);
    pk.w = f2bfu(s[3] * rden[d0 + 3]);
    *(ushort4*)((unsigned short*)ctxT + ((size_t)bh * 64 + e) * 64 + d0) = pk;
  }
}

// ---------------- attn: softmax(q)*DH^-.5 @ ctx -> attn_hm, MFMA -----------
// r12: output now LDS-repacked (reuse P) -> coalesced 128B/thread stores
// (was 64 scalar 2B stores/thread).
__global__ __launch_bounds__(256)
void attn_kernel(const bf16* __restrict__ qhm, const bf16* __restrict__ ctxT,
                 bf16* __restrict__ attn)
{
  int blk = blockIdx.x;           // bh*16 + chunk
  int chunk = blk & 15, bh = blk >> 4;
  int t = threadIdx.x, lane = t & 63, wid = t >> 6;
  __shared__ bf16 P[256 * 64];
  __shared__ bf16 CT[64 * 64];

  {
    const unsigned short* cg = (const unsigned short*)ctxT + (size_t)bh * 4096;
#pragma unroll
    for (int r = 0; r < 2; ++r) {
      int idx = r * 256 + t;
      int e = idx >> 3, b = idx & 7;
      bf16x8 v = *(const bf16x8*)(cg + idx * 8);
      *(bf16x8*)&CT[e * 64 + ((b ^ (e & 7)) * 8)] = v;
    }
  }
  {
    int s = chunk * 256 + t;
    const unsigned short* qp = (const unsigned short*)qhm + ((size_t)bh * 4096 + s) * 64;
    float p[64];
#pragma unroll
    for (int j = 0; j < 8; ++j) {
      bf16x8 q8 = *(const bf16x8*)(qp + j * 8);
#pragma unroll
      for (int i = 0; i < 8; ++i) p[j * 8 + i] = bf2f(q8[i]);
    }
    float mx = p[0];
#pragma unroll
    for (int d = 1; d < 64; ++d) mx = fmaxf(mx, p[d]);
    float sum = 0.f;
#pragma unroll
    for (int d = 0; d < 64; ++d) { p[d] = __expf(p[d] - mx); sum += p[d]; }
    float f = 0.125f / sum;       // DH^-0.5
    bf16* pb = &P[(t >> 6) * 4096 + (t & 63) * 64];
#pragma unroll
    for (int b = 0; b < 8; ++b) {
      bf16x8 pk;
#pragma unroll
      for (int i = 0; i < 8; ++i) pk[i] = (short)f2bfu(p[b * 8 + i] * f);
      *(bf16x8*)&pb[((b ^ (t & 7)) * 8)] = pk;
    }
  }
  __syncthreads();

  const int fr = lane & 15, g = lane >> 4;
  f32x4 acc[4][4] = {};
  const bf16* Pw = &P[wid * 4096];
#pragma unroll
  for (int ks = 0; ks < 2; ++ks) {
    bf16x8 av[4], bv[4];
#pragma unroll
    for (int mi = 0; mi < 4; ++mi) {
      int r = mi * 16 + fr;
      av[mi] = *(const bf16x8*)&Pw[r * 64 + (((ks * 4 + g) ^ (r & 7)) * 8)];
    }
#pragma unroll
    for (int ni = 0; ni < 4; ++ni) {
      int e = ni * 16 + fr;
      bv[ni] = *(const bf16x8*)&CT[e * 64 + (((ks * 4 + g) ^ (e & 7)) * 8)];
    }
#pragma unroll
    for (int mi = 0; mi < 4; ++mi)
#pragma unroll
      for (int ni = 0; ni < 4; ++ni)
        acc[mi][ni] = MFMA_(av[mi], bv[ni], acc[mi][ni], 0, 0, 0);
  }

  // repack into LDS (P space is dead), then coalesced row stores
  __syncthreads();
  unsigned short* ol = (unsigned short*)P;
#pragma unroll
  for (int mi = 0; mi < 4; ++mi)
#pragma unroll
    for (int ni = 0; ni < 4; ++ni) {
      int e = ni * 16 + fr;
      int u = e >> 3;
#pragma unroll
      for (int j = 0; j < 4; ++j) {
        int r = wid * 64 + mi * 16 + g * 4 + j;
        int st = u ^ (r & 7);
        ol[r * 64 + st * 8 + (e & 7)] = f2bfu(acc[mi][ni][j]);
      }
    }
  __syncthreads();
  {
    int r = t;
    unsigned short* og = (unsigned short*)attn +
        ((size_t)bh * 4096 + chunk * 256 + r) * 64;
#pragma unroll
    for (int u = 0; u < 8; ++u) {
      int st = u ^ (r & 7);
      bf16x8 v = *(const bf16x8*)&ol[r * 64 + st * 8];
      *(bf16x8*)(og + u * 8) = v;
    }
  }
}

// ---------------- ws layout (bytes) — total 160 MiB -------------------------
#define OFF_WQKVT  ((size_t)0)
#define OFF_WOT    ((size_t)6291456)
#define OFF_W1T    ((size_t)8388608)
#define OFF_W2T    ((size_t)10485760)
#define OFF_CTXT   ((size_t)12582912)
#define OFF_PCTX   ((size_t)13631488)
#define OFF_PDEN   ((size_t)22020096)
#define OFF_ATTN   ((size_t)33554432)
#define OFF_H      OFF_ATTN
#define OFF_QHM    ((size_t)67108864)
#define OFF_KT     ((size_t)100663296)
#define OFF_VT     ((size_t)134217728)
#define OFF_Z      OFF_QHM
#define OFF_X2B    OFF_KT
#define OFF_Y      OFF_VT

extern "C" void kernel_launch(void* const* d_in, const int* in_sizes, int n_in,
                              void* d_out, int out_size, void* d_ws, size_t ws_size,
                              hipStream_t stream)
{
  const float* x     = (const float*)d_in[0];
  const float* ln1_g = (const float*)d_in[1];
  const float* ln1_b = (const float*)d_in[2];
  const float* Wqkv  = (const float*)d_in[3];
  const float* Wo    = (const float*)d_in[4];
  const float* bo    = (const float*)d_in[5];
  const float* ln2_g = (const float*)d_in[6];
  const float* ln2_b = (const float*)d_in[7];
  const float* W1    = (const float*)d_in[8];
  const float* b1    = (const float*)d_in[9];
  const float* W2    = (const float*)d_in[10];
  const float* b2    = (const float*)d_in[11];
  float* out = (float*)d_out;
  char* ws = (char*)d_ws;

  bf16*  h     = (bf16*)(ws + OFF_H);
  bf16*  attn  = (bf16*)(ws + OFF_ATTN);
  bf16*  qhm   = (bf16*)(ws + OFF_QHM);
  bf16*  kT    = (bf16*)(ws + OFF_KT);
  bf16*  vT    = (bf16*)(ws + OFF_VT);
  bf16*  ctxT  = (bf16*)(ws + OFF_CTXT);
  float* pctx  = (float*)(ws + OFF_PCTX);
  float* pden  = (float*)(ws + OFF_PDEN);
  bf16*  x2b   = (bf16*)(ws + OFF_X2B);
  bf16*  y     = (bf16*)(ws + OFF_Y);
  bf16*  z     = (bf16*)(ws + OFF_Z);
  bf16*  wqkvt = (bf16*)(ws + OFF_WQKVT);
  bf16*  wot   = (bf16*)(ws + OFF_WOT);
  bf16*  w1t   = (bf16*)(ws + OFF_W1T);
  bf16*  w2t   = (bf16*)(ws + OFF_W2T);

  const size_t GEMM_LDS = 131072;

  prep_kernel<<<BS_ + 192 * 32, 256, 0, stream>>>(
      x, ln1_g, ln1_b, h, Wqkv, Wo, W1, W2, wqkvt, wot, w1t, w2t);

  // qkv gemm (8-wave proven): scatter epilogue -> q_hm, kT, vT
  gemm256<EPI_QKV, false><<<(N3_ / 256) * (BS_ / 256), 512, GEMM_LDS, stream>>>(
      h, wqkvt, nullptr, qhm, nullptr, nullptr, nullptr, kT, vT, BS_, N3_, D_);

  ctx_partial<<<512, 256, 0, stream>>>(kT, vT, pctx, pden);
  ctx_merge<<<64, 256, 0, stream>>>(pctx, pden, ctxT);

  attn_kernel<<<1024, 256, 0, stream>>>(qhm, ctxT, attn);

  gemm256<EPI_BIAS_RES_BF16, true><<<(D_ / 256) * (BS_ / 256), 512, GEMM_LDS, stream>>>(
      attn, wot, nullptr, x2b, bo, x, nullptr, nullptr, nullptr, BS_, D_, D_);

  ln_kernel<<<BS_, 256, 0, stream>>>(x2b, ln2_g, ln2_b, y);

  gemm256<EPI_BIAS_GELU_BF16, false><<<(D_ / 256) * (BS_ / 256), 512, GEMM_LDS, stream>>>(
      y, w1t, nullptr, z, b1, nullptr, nullptr, nullptr, nullptr, BS_, D_, D_);

  gemm256<EPI_BIAS_RESB_F32, false><<<(D_ / 256) * (BS_ / 256), 512, GEMM_LDS, stream>>>(
      z, w2t, out, nullptr, b2, nullptr, x2b, nullptr, nullptr, BS_, D_, D_);
}

// Round 13
// 351.217 us; speedup vs baseline: 1.0739x; 1.0158x over previous
//
#include <hip/hip_runtime.h>
#include <hip/hip_bf16.h>
#include <math.h>

#define B_   4
#define S_   4096
#define D_   1024
#define H_   16
#define DH_  64
#define BS_  (B_ * S_)     // 16384 rows
#define N3_  3072          // 3 * INNER

using bf16 = __hip_bfloat16;
typedef __attribute__((ext_vector_type(8))) short bf16x8;
typedef __attribute__((ext_vector_type(4))) float f32x4;

#define GAS __attribute__((address_space(1)))
#define LAS __attribute__((address_space(3)))

__device__ __forceinline__ void gload_lds16(const bf16* g, bf16* l) {
  __builtin_amdgcn_global_load_lds((const GAS void*)g, (LAS void*)l, 16, 0, 0);
}

__device__ __forceinline__ float bf2f(short u) {
  unsigned int x = ((unsigned int)(unsigned short)u) << 16;
  return __builtin_bit_cast(float, x);
}
__device__ __forceinline__ unsigned short f2bfu(float f) {
  bf16 t = __float2bfloat16(f);
  return *(unsigned short*)&t;
}

// ------------- fused prep: LN1(+PE) wave-per-row AND weight transpose ------
// grid: [0, BS_/4) = LN blocks (4 rows each, one wave per row, no barriers);
// [BS_/4, BS_/4+6144) = transpose tiles.
__global__ __launch_bounds__(256)
void prep_kernel(const float* __restrict__ x, const float* __restrict__ ln1_g,
                 const float* __restrict__ ln1_b, bf16* __restrict__ h,
                 const float* __restrict__ Wqkv, const float* __restrict__ Wo,
                 const float* __restrict__ W1, const float* __restrict__ W2,
                 bf16* __restrict__ wqkvt, bf16* __restrict__ wot,
                 bf16* __restrict__ w1t, bf16* __restrict__ w2t)
{
  int bid = blockIdx.x;
  int t = threadIdx.x;
  if (bid < BS_ / 4) {
    int wid = t >> 6, lane = t & 63;
    int row = bid * 4 + wid;
    const float4* xr = (const float4*)(x + (size_t)row * D_);
    float4 v[4];
    float s = 0.f, ss = 0.f;
#pragma unroll
    for (int c = 0; c < 4; ++c) {
      v[c] = xr[c * 64 + lane];
      s  += v[c].x + v[c].y + v[c].z + v[c].w;
      ss += v[c].x * v[c].x + v[c].y * v[c].y + v[c].z * v[c].z + v[c].w * v[c].w;
    }
#pragma unroll
    for (int o = 32; o > 0; o >>= 1) { s += __shfl_xor(s, o); ss += __shfl_xor(ss, o); }
    float mean = s * (1.0f / D_);
    float var  = ss * (1.0f / D_) - mean * mean;
    float rs   = rsqrtf(var + 1e-6f);
    const float C = -0.0089944730194f;   // -ln(10000)/1024
    float p = (float)(row & (S_ - 1));
#pragma unroll
    for (int c = 0; c < 4; ++c) {
      int idx = c * 64 + lane;
      int d0 = idx * 4;
      const float4 g4 = ((const float4*)ln1_g)[idx];
      const float4 b4 = ((const float4*)ln1_b)[idx];
      float o0 = (v[c].x - mean) * rs * g4.x + b4.x;
      float o1 = (v[c].y - mean) * rs * g4.y + b4.y;
      float o2 = (v[c].z - mean) * rs * g4.z + b4.z;
      float o3 = (v[c].w - mean) * rs * g4.w + b4.w;
      float sn, cs;
      __sincosf(p * __expf((float)d0 * C), &sn, &cs);        o0 += sn; o1 += cs;
      __sincosf(p * __expf((float)(d0 + 2) * C), &sn, &cs);  o2 += sn; o3 += cs;
      ushort4 pk;
      pk.x = f2bfu(o0); pk.y = f2bfu(o1); pk.z = f2bfu(o2); pk.w = f2bfu(o3);
      ((ushort4*)h)[(size_t)row * (D_ / 4) + idx] = pk;
    }
  } else {
    int e = bid - BS_ / 4;
    int gx = e % 192, ky = e / 192;
    __shared__ float tile[32][33];
    const float* W; bf16* Wt; int N, xo;
    if (gx < 96)        { W = Wqkv; Wt = wqkvt; N = N3_; xo = gx; }
    else if (gx < 128)  { W = Wo;   Wt = wot;   N = D_;  xo = gx - 96; }
    else if (gx < 160)  { W = W1;   Wt = w1t;   N = D_;  xo = gx - 128; }
    else                { W = W2;   Wt = w2t;   N = D_;  xo = gx - 160; }
    int n0 = xo * 32, k0 = ky * 32;
    int tx = t & 31, ty = t >> 5;
#pragma unroll
    for (int j = 0; j < 32; j += 8)
      tile[ty + j][tx] = W[(size_t)(k0 + ty + j) * N + n0 + tx];
    __syncthreads();
#pragma unroll
    for (int j = 0; j < 32; j += 8)
      Wt[(size_t)(n0 + ty + j) * 1024 + k0 + tx] = __float2bfloat16(tile[tx][ty + j]);
  }
}

// ---------------- LN2 bf16->bf16, wave-per-row (no barriers) ---------------
__global__ __launch_bounds__(256)
void ln_kernel(const bf16* __restrict__ Xb, const float* __restrict__ G,
               const float* __restrict__ Bv, bf16* __restrict__ out)
{
  int t = threadIdx.x;
  int wid = t >> 6, lane = t & 63;
  int row = blockIdx.x * 4 + wid;
  const ushort4* xr = (const ushort4*)Xb + (size_t)row * (D_ / 4);
  float4 v[4];
  float s = 0.f, ss = 0.f;
#pragma unroll
  for (int c = 0; c < 4; ++c) {
    ushort4 u = xr[c * 64 + lane];
    v[c].x = bf2f(u.x); v[c].y = bf2f(u.y); v[c].z = bf2f(u.z); v[c].w = bf2f(u.w);
    s  += v[c].x + v[c].y + v[c].z + v[c].w;
    ss += v[c].x * v[c].x + v[c].y * v[c].y + v[c].z * v[c].z + v[c].w * v[c].w;
  }
#pragma unroll
  for (int o = 32; o > 0; o >>= 1) { s += __shfl_xor(s, o); ss += __shfl_xor(ss, o); }
  float mean = s * (1.0f / D_);
  float var  = ss * (1.0f / D_) - mean * mean;
  float rs   = rsqrtf(var + 1e-6f);
#pragma unroll
  for (int c = 0; c < 4; ++c) {
    int idx = c * 64 + lane;
    const float4 g4 = ((const float4*)G)[idx];
    const float4 b4 = ((const float4*)Bv)[idx];
    ushort4 pk;
    pk.x = f2bfu((v[c].x - mean) * rs * g4.x + b4.x);
    pk.y = f2bfu((v[c].y - mean) * rs * g4.y + b4.y);
    pk.z = f2bfu((v[c].z - mean) * rs * g4.z + b4.z);
    pk.w = f2bfu((v[c].w - mean) * rs * g4.w + b4.w);
    ((ushort4*)out)[(size_t)row * (D_ / 4) + idx] = pk;
  }
}

// ---------------- 256x256 8-phase bf16 MFMA GEMM (proven r5-r10) -----------
enum { EPI_QKV = 0, EPI_BIAS_RES_BF16 = 1, EPI_BIAS_GELU_BF16 = 2, EPI_BIAS_RESB_F32 = 3 };

#define MFMA_ __builtin_amdgcn_mfma_f32_16x16x32_bf16

template<int EPI, bool AHM>
__global__ __launch_bounds__(512)
void gemm256(const bf16* __restrict__ A, const bf16* __restrict__ Bt,
             float* __restrict__ Cf, bf16* __restrict__ Cb,
             const float* __restrict__ bias, const float* __restrict__ resf,
             const bf16* __restrict__ resb,
             bf16* __restrict__ Ck, bf16* __restrict__ Cv,
             int M, int N, int K)
{
  extern __shared__ __align__(16) char smem[];
  bf16* lds = (bf16*)smem;

  const int t = threadIdx.x;
  const int wid = t >> 6, lane = t & 63;
  const int wr = wid >> 2, wc = wid & 3;        // 2 x 4 waves
  const int bid = blockIdx.x;
  const int c = bid & 7;
  const int w = bid >> 3;
  const int sst = w >> 4;
  const int ii = w & 15;
  const int txg = sst >> 1, tyg = sst & 1;
  const int iy = ii & 3, ix = ii >> 2;
  const int ty = c * 8 + tyg * 4 + iy;
  const int tx = txg * 4 + ix;
  const int m0 = ty << 8, n0 = tx << 8;

  const bf16* Ab = AHM
      ? A + (((size_t)(m0 >> 12) * 16) * 4096 + (m0 & 4095)) * 64
      : A + (size_t)m0 * K;
  const bf16* Bb = Bt + (size_t)n0 * K;

  const int srow = t >> 2;
  const int scol = (((t & 3) ^ ((t >> 3) & 3)) * 8);
  const int NT = K >> 6;
  const int fr = lane & 15;
  const int fksw = (((lane >> 4) ^ ((lane >> 1) & 3)) * 8);

  f32x4 acc[8][4] = {};

  #define LDSHALF(b, mat, kh) (lds + (((((b) << 1) + (mat)) << 1) + (kh)) * 8192)
  #define STAGE(bkt, akt, mat, kh) do {                                        \
    bf16* _dst = LDSHALF((bkt) & 1, (mat), (kh)) + t * 8;                      \
    const int _ktk = (akt);                                                    \
    if ((mat) == 0 && AHM) {                                                   \
      const bf16* _sb = Ab + (size_t)_ktk * 262144 + (size_t)srow * 64         \
                        + (kh) * 32 + scol;                                    \
      gload_lds16(_sb, _dst);                                                  \
      gload_lds16(_sb + 8192, _dst + 4096);                                    \
    } else {                                                                   \
      const bf16* _sb = ((mat) == 0 ? Ab : Bb) + (size_t)srow * K              \
                        + (_ktk << 6) + (kh) * 32 + scol;                      \
      gload_lds16(_sb, _dst);                                                  \
      gload_lds16(_sb + (size_t)128 * K, _dst + 4096);                         \
    }                                                                          \
  } while (0)

  STAGE(0, 0, 0, 0); STAGE(0, 0, 1, 0);
  STAGE(0, 0, 0, 1); STAGE(0, 0, 1, 1);
  asm volatile("s_waitcnt vmcnt(4)" ::: "memory");
  __builtin_amdgcn_s_barrier();

#pragma unroll 2
  for (int kt = 0; kt < NT; ++kt) {
    const int cur = kt & 1;
    const int nk = (kt + 1 < NT) ? (kt + 1) : (NT - 1);   // phantom = last tile
    const bf16* hA0 = LDSHALF(cur, 0, 0);
    const bf16* hB0 = LDSHALF(cur, 1, 0);
    const bf16* hA1 = LDSHALF(cur, 0, 1);
    const bf16* hB1 = LDSHALF(cur, 1, 1);
    bf16x8 a[8], b0, b1, b2, b3;

    // ---- phase 1 ----
#pragma unroll
    for (int mi = 0; mi < 8; ++mi)
      a[mi] = *(const bf16x8*)&hA0[(wr * 128 + mi * 16 + fr) * 32 + fksw];
    b0 = *(const bf16x8*)&hB0[(wc * 64 +  0 + fr) * 32 + fksw];
    b1 = *(const bf16x8*)&hB0[(wc * 64 + 16 + fr) * 32 + fksw];
    STAGE(kt + 1, nk, 0, 0);
    __builtin_amdgcn_s_barrier();
    __builtin_amdgcn_s_setprio(1);
#pragma unroll
    for (int mi = 0; mi < 8; ++mi) {
      acc[mi][0] = MFMA_(a[mi], b0, acc[mi][0], 0, 0, 0);
      acc[mi][1] = MFMA_(a[mi], b1, acc[mi][1], 0, 0, 0);
    }
    __builtin_amdgcn_s_setprio(0);
    __builtin_amdgcn_s_barrier();

    // ---- phase 2 ----
    b2 = *(const bf16x8*)&hB0[(wc * 64 + 32 + fr) * 32 + fksw];
    b3 = *(const bf16x8*)&hB0[(wc * 64 + 48 + fr) * 32 + fksw];
    STAGE(kt + 1, nk, 1, 0);
    __builtin_amdgcn_s_barrier();
    __builtin_amdgcn_s_setprio(1);
#pragma unroll
    for (int mi = 0; mi < 8; ++mi) {
      acc[mi][2] = MFMA_(a[mi], b2, acc[mi][2], 0, 0, 0);
      acc[mi][3] = MFMA_(a[mi], b3, acc[mi][3], 0, 0, 0);
    }
    __builtin_amdgcn_s_setprio(0);
    asm volatile("s_waitcnt vmcnt(4)" ::: "memory");
    __builtin_amdgcn_s_barrier();

    // ---- phase 3 ----
#pragma unroll
    for (int mi = 0; mi < 8; ++mi)
      a[mi] = *(const bf16x8*)&hA1[(wr * 128 + mi * 16 + fr) * 32 + fksw];
    b0 = *(const bf16x8*)&hB1[(wc * 64 +  0 + fr) * 32 + fksw];
    b1 = *(const bf16x8*)&hB1[(wc * 64 + 16 + fr) * 32 + fksw];
    STAGE(kt + 1, nk, 0, 1);
    __builtin_amdgcn_s_barrier();
    __builtin_amdgcn_s_setprio(1);
#pragma unroll
    for (int mi = 0; mi < 8; ++mi) {
      acc[mi][0] = MFMA_(a[mi], b0, acc[mi][0], 0, 0, 0);
      acc[mi][1] = MFMA_(a[mi], b1, acc[mi][1], 0, 0, 0);
    }
    __builtin_amdgcn_s_setprio(0);
    __builtin_amdgcn_s_barrier();

    // ---- phase 4 ----
    b2 = *(const bf16x8*)&hB1[(wc * 64 + 32 + fr) * 32 + fksw];
    b3 = *(const bf16x8*)&hB1[(wc * 64 + 48 + fr) * 32 + fksw];
    STAGE(kt + 1, nk, 1, 1);
    __builtin_amdgcn_s_barrier();
    __builtin_amdgcn_s_setprio(1);
#pragma unroll
    for (int mi = 0; mi < 8; ++mi) {
      acc[mi][2] = MFMA_(a[mi], b2, acc[mi][2], 0, 0, 0);
      acc[mi][3] = MFMA_(a[mi], b3, acc[mi][3], 0, 0, 0);
    }
    __builtin_amdgcn_s_setprio(0);
    asm volatile("s_waitcnt vmcnt(4)" ::: "memory");
    __builtin_amdgcn_s_barrier();
  }
  asm volatile("s_waitcnt vmcnt(0)" ::: "memory");

  // ======== epilogue ========
  unsigned short* ot = (unsigned short*)lds;

  const bool q_repack = (EPI == EPI_QKV) && (n0 < 1024);
  if (EPI != EPI_QKV || q_repack) {
#pragma unroll
    for (int mi = 0; mi < 8; ++mi) {
#pragma unroll
      for (int ni = 0; ni < 4; ++ni) {
#pragma unroll
        for (int j = 0; j < 4; ++j) {
          int row = wr * 128 + mi * 16 + (lane >> 4) * 4 + j;
          int col = wc * 64 + ni * 16 + fr;
          int u = col >> 3;
          int st = (u & ~7) | ((u ^ row) & 7);
          ot[row * 256 + st * 8 + (col & 7)] = f2bfu(acc[mi][ni][j]);
        }
      }
    }
    __syncthreads();
  }

  if (EPI == EPI_QKV) {
    const int brow = m0 >> 12;
    const int mrow = m0 & 4095;
    if (q_repack) {
      int tq = t & 3, trow = t >> 2;
#pragma unroll
      for (int p = 0; p < 2; ++p) {
        int row = p * 128 + trow;
        int sglob = mrow + row;
#pragma unroll
        for (int i = 0; i < 8; ++i) {
          int uu = i * 4 + tq;
          int hl = uu >> 3, k = uu & 7;
          int st = (uu & ~7) | ((uu ^ row) & 7);
          bf16x8 v = *(const bf16x8*)&ot[row * 256 + st * 8];
          unsigned short* dst = (unsigned short*)Cb +
            (((size_t)(brow * 16 + (n0 >> 6) + hl) * 4096 + sglob) * 64 + k * 8);
          *(bf16x8*)dst = v;
        }
      }
    } else {
      int qsel = n0 >> 10;
#pragma unroll
      for (int mi = 0; mi < 8; ++mi) {
        int sloc = mrow + wr * 128 + mi * 16 + (lane >> 4) * 4;
#pragma unroll
        for (int ni = 0; ni < 4; ++ni) {
          int col = n0 + wc * 64 + ni * 16 + fr;
          int hh = (col >> 6) & 15;
          int dd = col & 63;
          unsigned short* kp = (unsigned short*)(qsel == 1 ? Ck : Cv) +
            (((size_t)(brow * 16 + hh) * 64 + dd) * 4096 + sloc);
          ushort4 pk;
          pk.x = f2bfu(acc[mi][ni][0]); pk.y = f2bfu(acc[mi][ni][1]);
          pk.z = f2bfu(acc[mi][ni][2]); pk.w = f2bfu(acc[mi][ni][3]);
          *(ushort4*)kp = pk;
        }
      }
    }
  } else {
    int rlane = lane & 31;
    int rrow0 = lane >> 5;
    float bias8[8];
    *(float4*)&bias8[0] = *(const float4*)&bias[n0 + rlane * 8];
    *(float4*)&bias8[4] = *(const float4*)&bias[n0 + rlane * 8 + 4];
#pragma unroll 4
    for (int it = 0; it < 16; ++it) {
      int row = wid * 32 + it * 2 + rrow0;
      int st = (rlane & ~7) | ((rlane ^ row) & 7);
      bf16x8 v8 = *(const bf16x8*)&ot[row * 256 + st * 8];
      int grow = m0 + row;
      float o[8];
#pragma unroll
      for (int q = 0; q < 8; ++q) o[q] = bf2f(v8[q]) + bias8[q];
      if (EPI == EPI_BIAS_RES_BF16) {
        const float* rp = resf + (size_t)grow * N + n0 + rlane * 8;
        float4 r0 = *(const float4*)rp, r1 = *(const float4*)(rp + 4);
        o[0] += r0.x; o[1] += r0.y; o[2] += r0.z; o[3] += r0.w;
        o[4] += r1.x; o[5] += r1.y; o[6] += r1.z; o[7] += r1.w;
        bf16x8 wv;
#pragma unroll
        for (int q = 0; q < 8; ++q) wv[q] = (short)f2bfu(o[q]);
        *(bf16x8*)((unsigned short*)Cb + (size_t)grow * N + n0 + rlane * 8) = wv;
      } else if (EPI == EPI_BIAS_GELU_BF16) {
        bf16x8 wv;
#pragma unroll
        for (int q = 0; q < 8; ++q) {
          float u = o[q];
          u = 0.5f * u * (1.0f + erff(u * 0.70710678118654752f));
          wv[q] = (short)f2bfu(u);
        }
        *(bf16x8*)((unsigned short*)Cb + (size_t)grow * N + n0 + rlane * 8) = wv;
      } else {   // EPI_BIAS_RESB_F32
        const unsigned short* rp = (const unsigned short*)resb + (size_t)grow * N + n0 + rlane * 8;
        bf16x8 r8 = *(const bf16x8*)rp;
#pragma unroll
        for (int q = 0; q < 8; ++q) o[q] += bf2f(r8[q]);
        float4 s0, s1;
        s0.x = o[0]; s0.y = o[1]; s0.z = o[2]; s0.w = o[3];
        s1.x = o[4]; s1.y = o[5]; s1.z = o[6]; s1.w = o[7];
        float* op = Cf + (size_t)grow * N + n0 + rlane * 8;
        *(float4*)op = s0;
        *(float4*)(op + 4) = s1;
      }
    }
  }
  #undef STAGE
  #undef LDSHALF
}

// ---------------- ctx split-K partial: MFMA, den fused in-loop -------------
__global__ __launch_bounds__(256)
void ctx_partial(const bf16* __restrict__ kT, const bf16* __restrict__ vT,
                 float* __restrict__ pctx, float* __restrict__ pden)
{
  int blk = blockIdx.x;          // bh*8 + kc
  int kc = blk & 7, bh = blk >> 3;
  int t = threadIdx.x, lane = t & 63, wid = t >> 6;
  const int fr = lane & 15, g = lane >> 4;
  __shared__ float part[4][4096];
  __shared__ float dpart[4][64];

  f32x4 acc[4][4] = {};
  float dsum[4] = {0.f, 0.f, 0.f, 0.f};
  const unsigned short* kb = (const unsigned short*)kT + (size_t)bh * 64 * 4096;
  const unsigned short* vb = (const unsigned short*)vT + (size_t)bh * 64 * 4096;
  const int kbase = kc * 512 + wid * 128;
#pragma unroll
  for (int i = 0; i < 4; ++i) {
    int kofs = kbase + i * 32 + g * 8;
    bf16x8 av[4], bv[4];
#pragma unroll
    for (int mi = 0; mi < 4; ++mi) {
      bf16x8 kr = *(const bf16x8*)(kb + (size_t)(mi * 16 + fr) * 4096 + kofs);
      bf16x8 ae;
      float es = 0.f;
#pragma unroll
      for (int j = 0; j < 8; ++j) {
        float e = __expf(bf2f(kr[j]));
        es += e;
        ae[j] = (short)f2bfu(e);
      }
      dsum[mi] += es;
      av[mi] = ae;
      bv[mi] = *(const bf16x8*)(vb + (size_t)(mi * 16 + fr) * 4096 + kofs);
    }
#pragma unroll
    for (int mi = 0; mi < 4; ++mi)
#pragma unroll
      for (int ni = 0; ni < 4; ++ni)
        acc[mi][ni] = MFMA_(av[mi], bv[ni], acc[mi][ni], 0, 0, 0);
  }
#pragma unroll
  for (int mi = 0; mi < 4; ++mi) {
    dsum[mi] += __shfl_xor(dsum[mi], 16);
    dsum[mi] += __shfl_xor(dsum[mi], 32);
  }
#pragma unroll
  for (int mi = 0; mi < 4; ++mi)
#pragma unroll
    for (int ni = 0; ni < 4; ++ni)
      *(f32x4*)&part[wid][(mi * 4 + ni) * 256 + lane * 4] = acc[mi][ni];
  if (g == 0) {
#pragma unroll
    for (int mi = 0; mi < 4; ++mi) dpart[wid][mi * 16 + fr] = dsum[mi];
  }
  __syncthreads();
  int lane2 = t & 63, fg = t >> 6;
#pragma unroll
  for (int ff = 0; ff < 4; ++ff) {
    int f = fg * 4 + ff;
    f32x4 s = {};
#pragma unroll
    for (int ww = 0; ww < 4; ++ww)
      s += *(const f32x4*)&part[ww][f * 256 + lane2 * 4];
    *(f32x4*)&pctx[((size_t)blk * 16 + f) * 256 + lane2 * 4] = s;
  }
  if (t < 64)
    pden[blk * 64 + t] = dpart[0][t] + dpart[1][t] + dpart[2][t] + dpart[3][t];
}

// ---------------- attn: merge(pctx,pden) + softmax(q)@ctx -> attn_hm -------
// ctx_merge fused: each block reduces the 8 k-slice partials for its bh
// (L2-hot, 128KB/bh shared by 16 blocks), normalizes, packs CT in LDS.
__global__ __launch_bounds__(256)
void attn_kernel(const bf16* __restrict__ qhm, const float* __restrict__ pctx,
                 const float* __restrict__ pden, bf16* __restrict__ attn)
{
  int blk = blockIdx.x;           // bh*16 + chunk
  int chunk = blk & 15, bh = blk >> 4;
  int t = threadIdx.x, lane = t & 63, wid = t >> 6;
  __shared__ bf16 P[256 * 64];
  __shared__ bf16 CT[64 * 64];
  __shared__ float rden[64];

  // fused merge: frag sums in regs, rden in LDS
  int lane2 = t & 63, fg = t >> 6;
  int fr2 = lane2 & 15, g2 = lane2 >> 4;
  f32x4 fs[4];
#pragma unroll
  for (int ff = 0; ff < 4; ++ff) {
    int f = fg * 4 + ff;
    f32x4 s = {};
#pragma unroll
    for (int kc = 0; kc < 8; ++kc)
      s += *(const f32x4*)&pctx[(((size_t)(bh * 8 + kc)) * 16 + f) * 256 + lane2 * 4];
    fs[ff] = s;
  }
  if (t < 64) {
    float s = 0.f;
    for (int kc = 0; kc < 8; ++kc) s += pden[(bh * 8 + kc) * 64 + t];
    rden[t] = 1.0f / s;
  }
  __syncthreads();
#pragma unroll
  for (int ff = 0; ff < 4; ++ff) {
    int f = fg * 4 + ff;
    int mi = f >> 2, ni = f & 3;
    int e = ni * 16 + fr2;
    int d0 = mi * 16 + g2 * 4;
    ushort4 pk;
    pk.x = f2bfu(fs[ff][0] * rden[d0 + 0]);
    pk.y = f2bfu(fs[ff][1] * rden[d0 + 1]);
    pk.z = f2bfu(fs[ff][2] * rden[d0 + 2]);
    pk.w = f2bfu(fs[ff][3] * rden[d0 + 3]);
    *(ushort4*)&CT[e * 64 + (((d0 >> 3) ^ (e & 7)) * 8) + (d0 & 7)] = pk;
  }

  // q softmax, thread-per-row -> P (swizzled)
  {
    int s = chunk * 256 + t;
    const unsigned short* qp = (const unsigned short*)qhm + ((size_t)bh * 4096 + s) * 64;
    float p[64];
#pragma unroll
    for (int j = 0; j < 8; ++j) {
      bf16x8 q8 = *(const bf16x8*)(qp + j * 8);
#pragma unroll
      for (int i = 0; i < 8; ++i) p[j * 8 + i] = bf2f(q8[i]);
    }
    float mx = p[0];
#pragma unroll
    for (int d = 1; d < 64; ++d) mx = fmaxf(mx, p[d]);
    float sum = 0.f;
#pragma unroll
    for (int d = 0; d < 64; ++d) { p[d] = __expf(p[d] - mx); sum += p[d]; }
    float f = 0.125f / sum;       // DH^-0.5
    bf16* pb = &P[(t >> 6) * 4096 + (t & 63) * 64];
#pragma unroll
    for (int b = 0; b < 8; ++b) {
      bf16x8 pk;
#pragma unroll
      for (int i = 0; i < 8; ++i) pk[i] = (short)f2bfu(p[b * 8 + i] * f);
      *(bf16x8*)&pb[((b ^ (t & 7)) * 8)] = pk;
    }
  }
  __syncthreads();

  const int fr = lane & 15, g = lane >> 4;
  f32x4 acc[4][4] = {};
  const bf16* Pw = &P[wid * 4096];
#pragma unroll
  for (int ks = 0; ks < 2; ++ks) {
    bf16x8 av[4], bv[4];
#pragma unroll
    for (int mi = 0; mi < 4; ++mi) {
      int r = mi * 16 + fr;
      av[mi] = *(const bf16x8*)&Pw[r * 64 + (((ks * 4 + g) ^ (r & 7)) * 8)];
    }
#pragma unroll
    for (int ni = 0; ni < 4; ++ni) {
      int e = ni * 16 + fr;
      bv[ni] = *(const bf16x8*)&CT[e * 64 + (((ks * 4 + g) ^ (e & 7)) * 8)];
    }
#pragma unroll
    for (int mi = 0; mi < 4; ++mi)
#pragma unroll
      for (int ni = 0; ni < 4; ++ni)
        acc[mi][ni] = MFMA_(av[mi], bv[ni], acc[mi][ni], 0, 0, 0);
  }
  unsigned short* ob = (unsigned short*)attn +
      ((size_t)bh * 4096 + chunk * 256 + wid * 64) * 64;
#pragma unroll
  for (int mi = 0; mi < 4; ++mi)
#pragma unroll
    for (int ni = 0; ni < 4; ++ni) {
      int e = ni * 16 + fr;
#pragma unroll
      for (int j = 0; j < 4; ++j) {
        int r = mi * 16 + g * 4 + j;
        ob[(size_t)r * 64 + e] = f2bfu(acc[mi][ni][j]);
      }
    }
}

// ---------------- ws layout (bytes) — total 160 MiB -------------------------
#define OFF_WQKVT  ((size_t)0)
#define OFF_WOT    ((size_t)6291456)
#define OFF_W1T    ((size_t)8388608)
#define OFF_W2T    ((size_t)10485760)
#define OFF_PCTX   ((size_t)13631488)
#define OFF_PDEN   ((size_t)22020096)
#define OFF_ATTN   ((size_t)33554432)
#define OFF_H      OFF_ATTN
#define OFF_QHM    ((size_t)67108864)
#define OFF_KT     ((size_t)100663296)
#define OFF_VT     ((size_t)134217728)
#define OFF_Z      OFF_QHM
#define OFF_X2B    OFF_KT
#define OFF_Y      OFF_VT

extern "C" void kernel_launch(void* const* d_in, const int* in_sizes, int n_in,
                              void* d_out, int out_size, void* d_ws, size_t ws_size,
                              hipStream_t stream)
{
  const float* x     = (const float*)d_in[0];
  const float* ln1_g = (const float*)d_in[1];
  const float* ln1_b = (const float*)d_in[2];
  const float* Wqkv  = (const float*)d_in[3];
  const float* Wo    = (const float*)d_in[4];
  const float* bo    = (const float*)d_in[5];
  const float* ln2_g = (const float*)d_in[6];
  const float* ln2_b = (const float*)d_in[7];
  const float* W1    = (const float*)d_in[8];
  const float* b1    = (const float*)d_in[9];
  const float* W2    = (const float*)d_in[10];
  const float* b2    = (const float*)d_in[11];
  float* out = (float*)d_out;
  char* ws = (char*)d_ws;

  bf16*  h     = (bf16*)(ws + OFF_H);
  bf16*  attn  = (bf16*)(ws + OFF_ATTN);
  bf16*  qhm   = (bf16*)(ws + OFF_QHM);
  bf16*  kT    = (bf16*)(ws + OFF_KT);
  bf16*  vT    = (bf16*)(ws + OFF_VT);
  float* pctx  = (float*)(ws + OFF_PCTX);
  float* pden  = (float*)(ws + OFF_PDEN);
  bf16*  x2b   = (bf16*)(ws + OFF_X2B);
  bf16*  y     = (bf16*)(ws + OFF_Y);
  bf16*  z     = (bf16*)(ws + OFF_Z);
  bf16*  wqkvt = (bf16*)(ws + OFF_WQKVT);
  bf16*  wot   = (bf16*)(ws + OFF_WOT);
  bf16*  w1t   = (bf16*)(ws + OFF_W1T);
  bf16*  w2t   = (bf16*)(ws + OFF_W2T);

  const size_t GEMM_LDS = 131072;

  // LN1 (wave-per-row) + weight transposes, one launch
  prep_kernel<<<BS_ / 4 + 192 * 32, 256, 0, stream>>>(
      x, ln1_g, ln1_b, h, Wqkv, Wo, W1, W2, wqkvt, wot, w1t, w2t);

  // qkv gemm (8-wave proven): scatter epilogue -> q_hm, kT, vT
  gemm256<EPI_QKV, false><<<(N3_ / 256) * (BS_ / 256), 512, GEMM_LDS, stream>>>(
      h, wqkvt, nullptr, qhm, nullptr, nullptr, nullptr, kT, vT, BS_, N3_, D_);

  ctx_partial<<<512, 256, 0, stream>>>(kT, vT, pctx, pden);

  // attn (merge fused) -> attn_hm
  attn_kernel<<<1024, 256, 0, stream>>>(qhm, pctx, pden, attn);

  gemm256<EPI_BIAS_RES_BF16, true><<<(D_ / 256) * (BS_ / 256), 512, GEMM_LDS, stream>>>(
      attn, wot, nullptr, x2b, bo, x, nullptr, nullptr, nullptr, BS_, D_, D_);

  ln_kernel<<<BS_ / 4, 256, 0, stream>>>(x2b, ln2_g, ln2_b, y);

  gemm256<EPI_BIAS_GELU_BF16, false><<<(D_ / 256) * (BS_ / 256), 512, GEMM_LDS, stream>>>(
      y, w1t, nullptr, z, b1, nullptr, nullptr, nullptr, nullptr, BS_, D_, D_);

  gemm256<EPI_BIAS_RESB_F32, false><<<(D_ / 256) * (BS_ / 256), 512, GEMM_LDS, stream>>>(
      z, w2t, out, nullptr, b2, nullptr, x2b, nullptr, nullptr, BS_, D_, D_);
}